// Round 4
// baseline (4640.423 us; speedup 1.0000x reference)
//
#include <hip/hip_runtime.h>

typedef unsigned short u16;
typedef unsigned int   u32;

static const int Nn  = 100000;
static const int Ne  = 800000;
static const int Dd  = 64;
static const int Ll  = 3;

// ---- cumulative f32-weight offsets (inputs 4..21 concatenated into W) ----
static const int H_CUM[19] = {
  0, 86016, 86208, 98496, 98688, 101760, 101808, 103152, 103248,
  129360, 130176, 133248, 133440, 134208, 134400, 134592, 135360, 135552, 135744
};
static const int H_SZ[18] = {
  86016, 192, 12288, 192, 3072, 48, 1344, 96,
  26112, 816, 3072, 192, 768, 192, 192, 768, 192, 192
};

__device__ __forceinline__ float b2f(u16 v) {
  union { u32 u; float f; } x; x.u = ((u32)v) << 16; return x.f;
}
__device__ __forceinline__ u16 f2b(float f) {
  union { u32 u; float f; } x; x.f = f;
  u32 u = x.u;
  u32 r = (u + 0x7FFFu + ((u >> 16) & 1u)) >> 16;
  return (u16)r;
}

// ---- fold BN (eval) into A*x+B per layer; layout per layer (320 f32):
// [0:64]=A_in [64:128]=B_in [128:144]=A_msg [144:160]=B_msg
// [160:176]=A_upd [176:192]=B_upd [192:256]=A_out [256:320]=B_out
__global__ void k_bnprep(const float* __restrict__ W, float* __restrict__ bnAB) {
  int idx = blockIdx.x * blockDim.x + threadIdx.x;
  if (idx >= 480) return;
  int i = idx / 160, d0 = idx % 160;
  const float* src; float* dstA; float* dstB; int dim, d;
  if (d0 < 64)       { d = d0;      src = W + 133440 + i * 256; dim = 64; dstA = bnAB + i*320 + 0;   dstB = bnAB + i*320 + 64;  }
  else if (d0 < 80)  { d = d0 - 64; src = W + 134208 + i * 64;  dim = 16; dstA = bnAB + i*320 + 128; dstB = bnAB + i*320 + 144; }
  else if (d0 < 96)  { d = d0 - 80; src = W + 134400 + i * 64;  dim = 16; dstA = bnAB + i*320 + 160; dstB = bnAB + i*320 + 176; }
  else               { d = d0 - 96; src = W + 134592 + i * 256; dim = 64; dstA = bnAB + i*320 + 192; dstB = bnAB + i*320 + 256; }
  float g = src[0*dim+d], b = src[1*dim+d], m = src[2*dim+d], v = src[3*dim+d];
  float A = g * rsqrtf(v + 1e-5f);
  float B = b - m * A;
  dstA[d] = A; dstB[d] = B;
}

// ---- u[i] = normalize(pos[i]-pos[i-1]); u[0]=normalize(1,1,1) ----
__global__ void k_u(const float* __restrict__ posf, float* __restrict__ u) {
  int i = blockIdx.x * blockDim.x + threadIdx.x;
  if (i >= Nn) return;
  float ux, uy, uz;
  if (i == 0) { ux = uy = uz = 0.57735026918962584f; }
  else {
    float vx = posf[i*3+0] - posf[(i-1)*3+0];
    float vy = posf[i*3+1] - posf[(i-1)*3+1];
    float vz = posf[i*3+2] - posf[(i-1)*3+2];
    float nrm = sqrtf(vx*vx + vy*vy + vz*vz);
    float inv = 1.0f / fmaxf(nrm, 1e-12f);
    ux = vx*inv; uy = vy*inv; uz = vz*inv;
  }
  u[i*3+0] = ux; u[i*3+1] = uy; u[i*3+2] = uz;
}

// ---- frame[i] = [b, n, cross(b,n)] stored [j*3+k], j=spatial, k=basis ----
__global__ void k_frame(const float* __restrict__ u, float* __restrict__ frame) {
  int i = blockIdx.x * blockDim.x + threadIdx.x;
  if (i >= Nn) return;
  float bx, by, bz, nx, ny, nz;
  if (i < Nn - 1) {
    float ax = u[i*3+0], ay = u[i*3+1], az = u[i*3+2];
    float cx = u[(i+1)*3+0], cy = u[(i+1)*3+1], cz = u[(i+1)*3+2];
    float dx = ax-cx, dy = ay-cy, dz = az-cz;
    float n1 = sqrtf(dx*dx + dy*dy + dz*dz);
    float i1 = 1.0f / fmaxf(n1, 1e-12f);
    bx = dx*i1; by = dy*i1; bz = dz*i1;
    float qx = ay*cz - az*cy, qy = az*cx - ax*cz, qz = ax*cy - ay*cx;
    float n2 = sqrtf(qx*qx + qy*qy + qz*qz);
    float i2 = 1.0f / fmaxf(n2, 1e-12f);
    nx = qx*i2; ny = qy*i2; nz = qz*i2;
  } else {
    bx = by = bz = 0.57735026918962584f;
    nx = ny = nz = 0.57735026918962584f;
  }
  float ex = by*nz - bz*ny, ey = bz*nx - bx*nz, ez = bx*ny - by*nx;
  frame[i*9+0] = bx; frame[i*9+1] = nx; frame[i*9+2] = ex;
  frame[i*9+3] = by; frame[i*9+4] = ny; frame[i*9+5] = ey;
  frame[i*9+6] = bz; frame[i*9+7] = nz; frame[i*9+8] = ez;
}

// ---- degree count ----
__global__ void k_cnt(const int* __restrict__ EI, int* __restrict__ cnt) {
  int e = blockIdx.x * blockDim.x + threadIdx.x;
  if (e >= Ne) return;
  atomicAdd(&cnt[EI[Ne + e]], 1);
}

// ---- single-block exclusive scan of cnt -> rowptr, + deg_inv ----
__global__ __launch_bounds__(1024) void k_scan(const int* __restrict__ cnt, int* __restrict__ rowptr,
                       float* __restrict__ deginv) {
  __shared__ int sm[1024];
  __shared__ int carry;
  int t = threadIdx.x;
  if (t == 0) carry = 0;
  __syncthreads();
  for (int base = 0; base < Nn; base += 1024) {
    int i = base + t;
    int v = (i < Nn) ? cnt[i] : 0;
    sm[t] = v;
    __syncthreads();
    for (int off = 1; off < 1024; off <<= 1) {
      int x = (t >= off) ? sm[t - off] : 0;
      __syncthreads();
      sm[t] += x;
      __syncthreads();
    }
    int exc = sm[t] - v;
    if (i < Nn) {
      rowptr[i] = carry + exc;
      int dv = v > 1 ? v : 1;
      deginv[i] = 1.0f / (float)dv;
    }
    __syncthreads();
    if (t == 1023) carry += sm[1023];
    __syncthreads();
  }
  if (t == 0) rowptr[Nn] = carry;
}

__global__ void k_place(const int* __restrict__ EI, const int* __restrict__ rowptr,
                        int* __restrict__ fill, int* __restrict__ perm) {
  int e = blockIdx.x * blockDim.x + threadIdx.x;
  if (e >= Ne) return;
  int vout = EI[Ne + e];
  int p = atomicAdd(&fill[vout], 1);
  perm[rowptr[vout] + p] = e;
}

// ---- Y[n,r,k] = sum_c h[n,c]*W_rel[(r*64+c)*64+k]; S[n,k] = h@W_self + b_rel + b_self ----
__global__ __launch_bounds__(256) void k_rel(
    const float* __restrict__ h, const float* __restrict__ Wrel,
    const float* __restrict__ Wself, const float* __restrict__ brel,
    const float* __restrict__ bself, u16* __restrict__ Y, float* __restrict__ S) {
  __shared__ float hs[32][64];
  int tid = threadIdx.x;
  int lane = tid & 63, w = tid >> 6;
  int nb0 = blockIdx.x * 32;
#pragma unroll
  for (int r = 0; r < 8; r++) {
    int idx = r * 256 + tid;
    int row = idx >> 6, col = idx & 63;
    int node = nb0 + row;
    hs[row][col] = (node < Nn) ? h[(size_t)node * 64 + col] : 0.0f;
  }
  __syncthreads();
  int base = w * 8;
  float bias = brel[lane] + bself[lane];
  float acc[8][8];
#pragma unroll
  for (int m = 0; m < 8; m++) {
#pragma unroll
    for (int r = 0; r < 7; r++) acc[m][r] = 0.0f;
    acc[m][7] = bias;
  }
  for (int c = 0; c < 64; c++) {
    float wv[8];
#pragma unroll
    for (int r = 0; r < 7; r++) wv[r] = Wrel[(r*64 + c)*64 + lane];
    wv[7] = Wself[c*64 + lane];
#pragma unroll
    for (int m = 0; m < 8; m++) {
      float hv = hs[base + m][c];
#pragma unroll
      for (int r = 0; r < 8; r++) acc[m][r] += hv * wv[r];
    }
  }
#pragma unroll
  for (int m = 0; m < 8; m++) {
    int node = nb0 + base + m;
    if (node >= Nn) continue;
#pragma unroll
    for (int r = 0; r < 7; r++) Y[(size_t)node*448 + r*64 + lane] = f2b(acc[m][r]);
    S[(size_t)node*64 + lane] = acc[m][7];
  }
}

// ---- per-edge: recompute 14 edge feats; m1=relu(bn_msg(relu(bn_in(h[in]))@Wl1+b));
// a=relu(ef@Wk1+b); m_out = bilinear(a@Wk2+bk2, [1,m1]); atomic scatter ----
__global__ __launch_bounds__(256) void k_msg(
    const float* __restrict__ h, const float* __restrict__ posf, const float* __restrict__ frame,
    const int* __restrict__ EI,
    const float* __restrict__ Wl1, const float* __restrict__ bl1,
    const float* __restrict__ Wk1, const float* __restrict__ bk1,
    const float* __restrict__ Wk2, const float* __restrict__ bk2,
    const float* __restrict__ bn, float* __restrict__ upd2) {
  __shared__ float m1s[16][256];
  int tid = threadIdx.x;
  int e = blockIdx.x * 256 + tid;
  if (e >= Ne) return;
  int vin = EI[e], vout = EI[Ne + e];

  const float* Ain = bn + 0;
  const float* Bin = bn + 64;
  float m1[16];
#pragma unroll
  for (int j = 0; j < 16; j++) m1[j] = bl1[j];
  const float4* hr = (const float4*)(h + (size_t)vin * 64);
  for (int c4 = 0; c4 < 16; c4++) {
    float4 hv = hr[c4];
    int c = c4 * 4;
    float l0 = fmaxf(hv.x * Ain[c+0] + Bin[c+0], 0.0f);
    float l1 = fmaxf(hv.y * Ain[c+1] + Bin[c+1], 0.0f);
    float l2 = fmaxf(hv.z * Ain[c+2] + Bin[c+2], 0.0f);
    float l3 = fmaxf(hv.w * Ain[c+3] + Bin[c+3], 0.0f);
#pragma unroll
    for (int j = 0; j < 16; j++)
      m1[j] += l0 * Wl1[(c+0)*16 + j] + l1 * Wl1[(c+1)*16 + j]
             + l2 * Wl1[(c+2)*16 + j] + l3 * Wl1[(c+3)*16 + j];
  }
  const float* Amsg = bn + 128;
  const float* Bmsg = bn + 144;
#pragma unroll
  for (int j = 0; j < 16; j++)
    m1s[j][tid] = fmaxf(m1[j] * Amsg[j] + Bmsg[j], 0.0f);

  float fi[9], fo[9];
#pragma unroll
  for (int t = 0; t < 9; t++) fi[t] = frame[(size_t)vin*9 + t];
#pragma unroll
  for (int t = 0; t < 9; t++) fo[t] = frame[(size_t)vout*9 + t];
  float d0 = posf[vout*3+0] - posf[vin*3+0];
  float d1 = posf[vout*3+1] - posf[vin*3+1];
  float d2 = posf[vout*3+2] - posf[vin*3+2];
  float ef[14];
#pragma unroll
  for (int k = 0; k < 3; k++) {
    ef[k]   = fi[0*3+k]*d0 + fi[1*3+k]*d1 + fi[2*3+k]*d2;
    ef[3+k] = fi[0*3+k]*fo[0*3+k] + fi[1*3+k]*fo[1*3+k] + fi[2*3+k]*fo[2*3+k];
  }
  int ad = vin - vout; if (ad < 0) ad = -ad;
  ef[6] = ((float)ad) / 6.0f;
#pragma unroll
  for (int k = 0; k < 7; k++) ef[7+k] = 1.0f - 2.0f*fabsf(ef[k]);

  float a[32];
#pragma unroll
  for (int q = 0; q < 32; q++) a[q] = bk1[q];
#pragma unroll
  for (int d = 0; d < 14; d++) {
    float fv = ef[d];
#pragma unroll
    for (int q = 0; q < 32; q++) a[q] += fv * Wk1[d*32 + q];
  }
#pragma unroll
  for (int q = 0; q < 32; q++) a[q] = fmaxf(a[q], 0.0f);

  float mo[16];
#pragma unroll
  for (int k = 0; k < 16; k++) mo[k] = 0.0f;
  for (int jp = 0; jp < 17; jp++) {
    float t[16];
#pragma unroll
    for (int k = 0; k < 16; k++) t[k] = bk2[jp*16 + k];
#pragma unroll
    for (int q = 0; q < 32; q++) {
      float av = a[q];
      const float* wr = Wk2 + q*272 + jp*16;
#pragma unroll
      for (int k = 0; k < 16; k++) t[k] += av * wr[k];
    }
    float coeff = (jp == 0) ? 1.0f : m1s[jp-1][tid];
#pragma unroll
    for (int k = 0; k < 16; k++) mo[k] += coeff * t[k];
  }
  float* dst = upd2 + (size_t)vout * 16;
#pragma unroll
  for (int k = 0; k < 16; k++) atomicAdd(dst + k, mo[k]);
}

// ---- per-node: rel gather from Y + S, upd2 path, residual, LayerNorm -> f32 out ----
__global__ __launch_bounds__(256) void k_node(
    const float* __restrict__ h, const float* __restrict__ S, const u16* __restrict__ Y,
    const int* __restrict__ rowptr, const int* __restrict__ perm,
    const int* __restrict__ EI, const int* __restrict__ EREL,
    const float* __restrict__ upd2, const float* __restrict__ deginv,
    const float* __restrict__ Wl2, const float* __restrict__ bl2,
    const float* __restrict__ bn, const float* __restrict__ lng, const float* __restrict__ lnb,
    float* __restrict__ hout) {
  __shared__ float u2s[4][16];
  int tid = threadIdx.x;
  int lane = tid & 63, w = tid >> 6;
  int n = blockIdx.x * 4 + w;
  bool act = (n < Nn);

  float acc = 0.0f;
  if (act) {
    acc = S[(size_t)n*64 + lane];
    int beg = rowptr[n], end = rowptr[n+1];
    for (int p = beg; p < end; p++) {
      int e = perm[p];
      int vin = EI[e];
      int rel = EREL[e];
      acc += b2f(Y[(size_t)vin*448 + rel*64 + lane]);
    }
  }
  const float* Aupd = bn + 160;
  const float* Bupd = bn + 176;
  if (act && lane < 16) {
    float v = upd2[(size_t)n*16 + lane] * deginv[n];
    u2s[w][lane] = fmaxf(v * Aupd[lane] + Bupd[lane], 0.0f);
  }
  __syncthreads();
  if (act) {
    float rel_out = fmaxf(acc, 0.0f);
    float ie = bl2[lane];
#pragma unroll
    for (int j = 0; j < 16; j++) ie += u2s[w][j] * Wl2[j*64 + lane];
    const float* Aout = bn + 192;
    const float* Bout = bn + 256;
    ie = ie * Aout[lane] + Bout[lane];
    float hidden = rel_out + ie + h[(size_t)n*64 + lane];
    float s = hidden;
#pragma unroll
    for (int off = 32; off > 0; off >>= 1) s += __shfl_xor(s, off, 64);
    float mu = s * (1.0f/64.0f);
    float d = hidden - mu;
    float s2 = d * d;
#pragma unroll
    for (int off = 32; off > 0; off >>= 1) s2 += __shfl_xor(s2, off, 64);
    float var = s2 * (1.0f/64.0f);
    float o = d * rsqrtf(var + 1e-5f) * lng[lane] + lnb[lane];
    hout[(size_t)n*64 + lane] = o;
  }
}

extern "C" void kernel_launch(void* const* d_in, const int* in_sizes, int n_in,
                              void* d_out, int out_size, void* d_ws, size_t ws_size,
                              hipStream_t stream) {
  const float* x    = (const float*)d_in[0];   // inputs are f32 (proven R3: dtype detector)
  const float* posf = (const float*)d_in[1];
  const int* EI     = (const int*)d_in[2];
  const int* EREL   = (const int*)d_in[3];
  float* outf       = (float*)d_out;           // reference output dtype = float32

  char* p = (char*)d_ws;
  auto alloc = [&](size_t bytes) -> char* {
    char* r = p;
    p += (bytes + 255) & ~((size_t)255);
    return r;
  };
  float* W      = (float*)alloc((size_t)135744 * 4);
  float* bnAB   = (float*)alloc((size_t)960 * 4);
  float* u      = (float*)alloc((size_t)Nn * 3 * 4);
  float* frame  = (float*)alloc((size_t)Nn * 9 * 4);
  int*   cnt    = (int*)  alloc((size_t)Nn * 4);
  int*   fill   = (int*)  alloc((size_t)Nn * 4);
  int*   rowptr = (int*)  alloc((size_t)(Nn + 1) * 4);
  int*   perm   = (int*)  alloc((size_t)Ne * 4);
  float* deginv = (float*)alloc((size_t)Nn * 4);
  float* h      = (float*)alloc((size_t)Nn * 64 * 4);
  float* S      = (float*)alloc((size_t)Nn * 64 * 4);
  u16*   Y      = (u16*)  alloc((size_t)Nn * 448 * 2);
  float* upd2   = (float*)alloc((size_t)Nn * 16 * 4);
  (void)n_in; (void)in_sizes; (void)out_size;

  size_t needed = (size_t)(p - (char*)d_ws);
  if (needed > ws_size) return;  // diagnostic: zeros out -> absmax == max|ref| (~4.75)

  hipMemsetAsync(cnt,  0, (size_t)Nn * 4, stream);
  hipMemsetAsync(fill, 0, (size_t)Nn * 4, stream);

  // weights: d2d copies into one contiguous f32 block
  for (int k = 0; k < 18; k++)
    hipMemcpyAsync(W + H_CUM[k], d_in[4 + k], (size_t)H_SZ[k] * 4,
                   hipMemcpyDeviceToDevice, stream);
  // h0 = x
  hipMemcpyAsync(h, x, (size_t)Nn * 64 * 4, hipMemcpyDeviceToDevice, stream);

  k_bnprep<<<2, 256, 0, stream>>>(W, bnAB);
  k_u<<<(Nn + 255)/256, 256, 0, stream>>>(posf, u);
  k_frame<<<(Nn + 255)/256, 256, 0, stream>>>(u, frame);
  k_cnt<<<Ne/256, 256, 0, stream>>>(EI, cnt);
  k_scan<<<1, 1024, 0, stream>>>(cnt, rowptr, deginv);
  k_place<<<Ne/256, 256, 0, stream>>>(EI, rowptr, fill, perm);

  for (int i = 0; i < Ll; i++) {
    const float* Wrel  = W + H_CUM[0]  + i * 28672;
    const float* brel  = W + H_CUM[1]  + i * 64;
    const float* Wself = W + H_CUM[2]  + i * 4096;
    const float* bself = W + H_CUM[3]  + i * 64;
    const float* Wl1   = W + H_CUM[4]  + i * 1024;
    const float* bl1   = W + H_CUM[5]  + i * 16;
    const float* Wk1   = W + H_CUM[6]  + i * 448;
    const float* bk1   = W + H_CUM[7]  + i * 32;
    const float* Wk2   = W + H_CUM[8]  + i * 8704;
    const float* bk2   = W + H_CUM[9]  + i * 272;
    const float* Wl2   = W + H_CUM[10] + i * 1024;
    const float* bl2   = W + H_CUM[11] + i * 64;
    const float* lng   = W + H_CUM[16] + i * 64;
    const float* lnb   = W + H_CUM[17] + i * 64;
    const float* bnL   = bnAB + i * 320;

    hipMemsetAsync(upd2, 0, (size_t)Nn * 16 * 4, stream);
    k_rel<<<Nn/32, 256, 0, stream>>>(h, Wrel, Wself, brel, bself, Y, S);
    k_msg<<<Ne/256, 256, 0, stream>>>(h, posf, frame, EI, Wl1, bl1, Wk1, bk1, Wk2, bk2, bnL, upd2);
    k_node<<<(Nn + 3)/4, 256, 0, stream>>>(h, S, Y, rowptr, perm, EI, EREL, upd2, deginv,
                                           Wl2, bl2, bnL, lng, lnb,
                                           (i == Ll - 1) ? outf : h);
  }
}

// Round 6
// 1807.470 us; speedup vs baseline: 2.5674x; 2.5674x over previous
//
#include <hip/hip_runtime.h>

typedef unsigned short u16;
typedef unsigned int   u32;

static const int Nn  = 100000;
static const int Ne  = 800000;
static const int Dd  = 64;
static const int Ll  = 3;

typedef short     short8  __attribute__((ext_vector_type(8)));
typedef float     floatx4 __attribute__((ext_vector_type(4)));

// ---- cumulative f32-weight offsets (inputs 4..21 concatenated into W) ----
static const int H_CUM[19] = {
  0, 86016, 86208, 98496, 98688, 101760, 101808, 103152, 103248,
  129360, 130176, 133248, 133440, 134208, 134400, 134592, 135360, 135552, 135744
};
static const int H_SZ[18] = {
  86016, 192, 12288, 192, 3072, 48, 1344, 96,
  26112, 816, 3072, 192, 768, 192, 192, 768, 192, 192
};

__device__ __forceinline__ float b2f(u16 v) {
  union { u32 u; float f; } x; x.u = ((u32)v) << 16; return x.f;
}
__device__ __forceinline__ u16 f2b(float f) {
  union { u32 u; float f; } x; x.f = f;
  u32 u = x.u;
  u32 r = (u + 0x7FFFu + ((u >> 16) & 1u)) >> 16;
  return (u16)r;
}

// ---- fold BN (eval) into A*x+B per layer; layout per layer (320 f32) ----
__global__ void k_bnprep(const float* __restrict__ W, float* __restrict__ bnAB) {
  int idx = blockIdx.x * blockDim.x + threadIdx.x;
  if (idx >= 480) return;
  int i = idx / 160, d0 = idx % 160;
  const float* src; float* dstA; float* dstB; int dim, d;
  if (d0 < 64)       { d = d0;      src = W + 133440 + i * 256; dim = 64; dstA = bnAB + i*320 + 0;   dstB = bnAB + i*320 + 64;  }
  else if (d0 < 80)  { d = d0 - 64; src = W + 134208 + i * 64;  dim = 16; dstA = bnAB + i*320 + 128; dstB = bnAB + i*320 + 144; }
  else if (d0 < 96)  { d = d0 - 80; src = W + 134400 + i * 64;  dim = 16; dstA = bnAB + i*320 + 160; dstB = bnAB + i*320 + 176; }
  else               { d = d0 - 96; src = W + 134592 + i * 256; dim = 64; dstA = bnAB + i*320 + 192; dstB = bnAB + i*320 + 256; }
  float g = src[0*dim+d], b = src[1*dim+d], m = src[2*dim+d], v = src[3*dim+d];
  float A = g * rsqrtf(v + 1e-5f);
  float B = b - m * A;
  dstA[d] = A; dstB[d] = B;
}

// ---- Bsw prep: B-fragment-ordered bf16 Wk2, K order flat = jp*32+q.
// Bsw[layer][jp][lane][j] = Wk2[q = (lane>>4)*8+j][jp][n = lane&15] ----
__global__ void k_prep(const float* __restrict__ W, u16* __restrict__ BswG) {
  int i = blockIdx.x * 256 + threadIdx.x;
  if (i >= 3 * 8704) return;
  int layer = i / 8704, r = i % 8704;
  int jp = r / 512, l2 = r % 512;
  int lane = l2 / 8, j = l2 % 8;
  int q = (lane >> 4) * 8 + j, n = lane & 15;
  const float* Wk2 = W + 103248 + layer * 8704;
  BswG[i] = f2b(Wk2[q * 272 + jp * 16 + n]);
}

// ---- u[i] = normalize(pos[i]-pos[i-1]); u[0]=normalize(1,1,1) ----
__global__ void k_u(const float* __restrict__ posf, float* __restrict__ u) {
  int i = blockIdx.x * blockDim.x + threadIdx.x;
  if (i >= Nn) return;
  float ux, uy, uz;
  if (i == 0) { ux = uy = uz = 0.57735026918962584f; }
  else {
    float vx = posf[i*3+0] - posf[(i-1)*3+0];
    float vy = posf[i*3+1] - posf[(i-1)*3+1];
    float vz = posf[i*3+2] - posf[(i-1)*3+2];
    float nrm = sqrtf(vx*vx + vy*vy + vz*vz);
    float inv = 1.0f / fmaxf(nrm, 1e-12f);
    ux = vx*inv; uy = vy*inv; uz = vz*inv;
  }
  u[i*3+0] = ux; u[i*3+1] = uy; u[i*3+2] = uz;
}

// ---- frame[i] = [b, n, cross(b,n)] stored [j*3+k], j=spatial, k=basis ----
__global__ void k_frame(const float* __restrict__ u, float* __restrict__ frame) {
  int i = blockIdx.x * blockDim.x + threadIdx.x;
  if (i >= Nn) return;
  float bx, by, bz, nx, ny, nz;
  if (i < Nn - 1) {
    float ax = u[i*3+0], ay = u[i*3+1], az = u[i*3+2];
    float cx = u[(i+1)*3+0], cy = u[(i+1)*3+1], cz = u[(i+1)*3+2];
    float dx = ax-cx, dy = ay-cy, dz = az-cz;
    float n1 = sqrtf(dx*dx + dy*dy + dz*dz);
    float i1 = 1.0f / fmaxf(n1, 1e-12f);
    bx = dx*i1; by = dy*i1; bz = dz*i1;
    float qx = ay*cz - az*cy, qy = az*cx - ax*cz, qz = ax*cy - ay*cx;
    float n2 = sqrtf(qx*qx + qy*qy + qz*qz);
    float i2 = 1.0f / fmaxf(n2, 1e-12f);
    nx = qx*i2; ny = qy*i2; nz = qz*i2;
  } else {
    bx = by = bz = 0.57735026918962584f;
    nx = ny = nz = 0.57735026918962584f;
  }
  float ex = by*nz - bz*ny, ey = bz*nx - bx*nz, ez = bx*ny - by*nx;
  frame[i*9+0] = bx; frame[i*9+1] = nx; frame[i*9+2] = ex;
  frame[i*9+3] = by; frame[i*9+4] = ny; frame[i*9+5] = ey;
  frame[i*9+6] = bz; frame[i*9+7] = nz; frame[i*9+8] = ez;
}

// ---- degree count ----
__global__ void k_cnt(const int* __restrict__ EI, int* __restrict__ cnt) {
  int e = blockIdx.x * blockDim.x + threadIdx.x;
  if (e >= Ne) return;
  atomicAdd(&cnt[EI[Ne + e]], 1);
}

// ---- single-block exclusive scan of cnt -> rowptr, + deg_inv ----
__global__ __launch_bounds__(1024) void k_scan(const int* __restrict__ cnt, int* __restrict__ rowptr,
                       float* __restrict__ deginv) {
  __shared__ int sm[1024];
  __shared__ int carry;
  int t = threadIdx.x;
  if (t == 0) carry = 0;
  __syncthreads();
  for (int base = 0; base < Nn; base += 1024) {
    int i = base + t;
    int v = (i < Nn) ? cnt[i] : 0;
    sm[t] = v;
    __syncthreads();
    for (int off = 1; off < 1024; off <<= 1) {
      int x = (t >= off) ? sm[t - off] : 0;
      __syncthreads();
      sm[t] += x;
      __syncthreads();
    }
    int exc = sm[t] - v;
    if (i < Nn) {
      rowptr[i] = carry + exc;
      int dv = v > 1 ? v : 1;
      deginv[i] = 1.0f / (float)dv;
    }
    __syncthreads();
    if (t == 1023) carry += sm[1023];
    __syncthreads();
  }
  if (t == 0) rowptr[Nn] = carry;
}

__global__ void k_place(const int* __restrict__ EI, const int* __restrict__ rowptr,
                        int* __restrict__ fill, int* __restrict__ perm) {
  int e = blockIdx.x * blockDim.x + threadIdx.x;
  if (e >= Ne) return;
  int vout = EI[Ne + e];
  int p = atomicAdd(&fill[vout], 1);
  perm[rowptr[vout] + p] = e;
}

// ---- Y[n,r,k]; S[n,k] (both bf16) ----
__global__ __launch_bounds__(256) void k_rel(
    const float* __restrict__ h, const float* __restrict__ Wrel,
    const float* __restrict__ Wself, const float* __restrict__ brel,
    const float* __restrict__ bself, u16* __restrict__ Y, u16* __restrict__ S) {
  __shared__ float hs[32][64];
  int tid = threadIdx.x;
  int lane = tid & 63, w = tid >> 6;
  int nb0 = blockIdx.x * 32;
#pragma unroll
  for (int r = 0; r < 8; r++) {
    int idx = r * 256 + tid;
    int row = idx >> 6, col = idx & 63;
    int node = nb0 + row;
    hs[row][col] = (node < Nn) ? h[(size_t)node * 64 + col] : 0.0f;
  }
  __syncthreads();
  int base = w * 8;
  float bias = brel[lane] + bself[lane];
  float acc[8][8];
#pragma unroll
  for (int m = 0; m < 8; m++) {
#pragma unroll
    for (int r = 0; r < 7; r++) acc[m][r] = 0.0f;
    acc[m][7] = bias;
  }
  for (int c = 0; c < 64; c++) {
    float wv[8];
#pragma unroll
    for (int r = 0; r < 7; r++) wv[r] = Wrel[(r*64 + c)*64 + lane];
    wv[7] = Wself[c*64 + lane];
#pragma unroll
    for (int m = 0; m < 8; m++) {
      float hv = hs[base + m][c];
#pragma unroll
      for (int r = 0; r < 8; r++) acc[m][r] += hv * wv[r];
    }
  }
#pragma unroll
  for (int m = 0; m < 8; m++) {
    int node = nb0 + base + m;
    if (node >= Nn) continue;
#pragma unroll
    for (int r = 0; r < 7; r++) Y[(size_t)node*448 + r*64 + lane] = f2b(acc[m][r]);
    S[(size_t)node*64 + lane] = f2b(acc[m][7]);
  }
}

// ---- per-edge MFMA kernel ----
__global__ __launch_bounds__(256) void k_msg(
    const float* __restrict__ h, const float* __restrict__ posf, const float* __restrict__ frame,
    const int* __restrict__ EI,
    const float* __restrict__ Wl1, const float* __restrict__ bl1,
    const float* __restrict__ Wk1, const float* __restrict__ bk1,
    const u16* __restrict__ BswG, const float* __restrict__ bk2,
    const float* __restrict__ bn, u16* __restrict__ mo) {
  __shared__ u16   abuf[256 * 40];   // 32 bf16 used/row, stride 40 u16 (80 B)
  __shared__ float zbuf[256 * 20];   // 16 f32 used/row (m1), stride 20 (80 B)
  __shared__ u32   bsw[4352];        // 17*64*8 bf16 B-fragments

  int tid = threadIdx.x;
  int e0 = blockIdx.x * 256;
  int e = e0 + tid;

  for (int i = tid; i < 4352; i += 256) bsw[i] = ((const u32*)BswG)[i];

  int vin = EI[e], vout = EI[Ne + e];

  // ---- m1 = relu(bn_msg(relu(bn_in(h[vin])) @ Wl1 + bl1)) -> zbuf ----
  const float* Ain = bn + 0;
  const float* Bin = bn + 64;
  float m1[16];
#pragma unroll
  for (int j = 0; j < 16; j++) m1[j] = bl1[j];
  const float4* hr = (const float4*)(h + (size_t)vin * 64);
  for (int c4 = 0; c4 < 16; c4++) {
    float4 hv = hr[c4];
    int c = c4 * 4;
    float l0 = fmaxf(hv.x * Ain[c+0] + Bin[c+0], 0.0f);
    float l1 = fmaxf(hv.y * Ain[c+1] + Bin[c+1], 0.0f);
    float l2 = fmaxf(hv.z * Ain[c+2] + Bin[c+2], 0.0f);
    float l3 = fmaxf(hv.w * Ain[c+3] + Bin[c+3], 0.0f);
#pragma unroll
    for (int j = 0; j < 16; j++)
      m1[j] += l0 * Wl1[(c+0)*16 + j] + l1 * Wl1[(c+1)*16 + j]
             + l2 * Wl1[(c+2)*16 + j] + l3 * Wl1[(c+3)*16 + j];
  }
  const float* Amsg = bn + 128;
  const float* Bmsg = bn + 144;
  float* zr = zbuf + (size_t)tid * 20;
#pragma unroll
  for (int j = 0; j < 16; j++)
    zr[j] = fmaxf(m1[j] * Amsg[j] + Bmsg[j], 0.0f);

  // ---- edge features + a = relu(ef @ Wk1 + bk1) -> abuf (bf16) ----
  float fi[9], fo[9];
#pragma unroll
  for (int t = 0; t < 9; t++) fi[t] = frame[(size_t)vin*9 + t];
#pragma unroll
  for (int t = 0; t < 9; t++) fo[t] = frame[(size_t)vout*9 + t];
  float d0 = posf[vout*3+0] - posf[vin*3+0];
  float d1 = posf[vout*3+1] - posf[vin*3+1];
  float d2 = posf[vout*3+2] - posf[vin*3+2];
  float ef[14];
#pragma unroll
  for (int k = 0; k < 3; k++) {
    ef[k]   = fi[0*3+k]*d0 + fi[1*3+k]*d1 + fi[2*3+k]*d2;
    ef[3+k] = fi[0*3+k]*fo[0*3+k] + fi[1*3+k]*fo[1*3+k] + fi[2*3+k]*fo[2*3+k];
  }
  int ad = vin - vout; if (ad < 0) ad = -ad;
  ef[6] = ((float)ad) / 6.0f;
#pragma unroll
  for (int k = 0; k < 7; k++) ef[7+k] = 1.0f - 2.0f*fabsf(ef[k]);

  float a[32];
#pragma unroll
  for (int q = 0; q < 32; q++) a[q] = bk1[q];
#pragma unroll
  for (int d = 0; d < 14; d++) {
    float fv = ef[d];
#pragma unroll
    for (int q = 0; q < 32; q++) a[q] += fv * Wk1[d*32 + q];
  }
  u32* ar = (u32*)(abuf + (size_t)tid * 40);
#pragma unroll
  for (int q = 0; q < 16; q++) {
    u32 lo = f2b(fmaxf(a[2*q],   0.0f));
    u32 hi = f2b(fmaxf(a[2*q+1], 0.0f));
    ar[q] = lo | (hi << 16);
  }
  __syncthreads();

  // ---- phase 2: MFMA ----
  int lane = tid & 63, w = tid >> 6;
  int m = lane & 15, quad = lane >> 4;
#pragma unroll
  for (int t = 0; t < 4; t++) {
    int s0 = (w * 4 + t) * 16;
    int s = s0 + m;
    union U { uint4 u; short8 v; u16 h[8]; };
    U afr;
    afr.u = *(const uint4*)(abuf + (size_t)s * 40 + quad * 8);
    float av[8];
#pragma unroll
    for (int j = 0; j < 8; j++) av[j] = b2f(afr.h[j]);

    floatx4 acc = {0.0f, 0.0f, 0.0f, 0.0f};
    U bfr;
    bfr.u = *(const uint4*)(bsw + (size_t)(0 * 64 + lane) * 4);
    acc = __builtin_amdgcn_mfma_f32_16x16x32_bf16(afr.v, bfr.v, acc, 0, 0, 0);

    const float* zs = zbuf + (size_t)s * 20;
#pragma unroll
    for (int jp = 1; jp < 17; jp++) {
      float zv = zs[jp - 1];
      U pf;
#pragma unroll
      for (int j = 0; j < 4; j++) {
        u32 lo = f2b(av[2*j]   * zv);
        u32 hi = f2b(av[2*j+1] * zv);
        ((u32*)&pf.u)[j] = lo | (hi << 16);
      }
      bfr.u = *(const uint4*)(bsw + (size_t)(jp * 64 + lane) * 4);
      acc = __builtin_amdgcn_mfma_f32_16x16x32_bf16(pf.v, bfr.v, acc, 0, 0, 0);
    }

    // epilogue: lane holds D[row=quad*4+reg][col=k=lane&15]
    int k = m;
#pragma unroll
    for (int reg = 0; reg < 4; reg++) {
      int se = s0 + quad * 4 + reg;
      const float* zz = zbuf + (size_t)se * 20;
      float bias = bk2[k];
#pragma unroll
      for (int j = 0; j < 16; j++) bias += zz[j] * bk2[(j + 1) * 16 + k];
      mo[(size_t)(e0 + se) * 16 + k] = f2b(acc[reg] + bias);
    }
  }
}

// ---- per-node: rel gather from Y + S, mo gather (CSR) for upd2, residual, LN ----
__global__ __launch_bounds__(256) void k_node(
    const float* __restrict__ h, const u16* __restrict__ S, const u16* __restrict__ Y,
    const int* __restrict__ rowptr, const int* __restrict__ perm,
    const int* __restrict__ EI, const int* __restrict__ EREL,
    const u16* __restrict__ mo, const float* __restrict__ deginv,
    const float* __restrict__ Wl2, const float* __restrict__ bl2,
    const float* __restrict__ bn, const float* __restrict__ lng, const float* __restrict__ lnb,
    float* __restrict__ hout) {
  __shared__ float u2s[4][16];
  int tid = threadIdx.x;
  int lane = tid & 63, w = tid >> 6;
  int n = blockIdx.x * 4 + w;
  bool act = (n < Nn);

  float acc = 0.0f;
  float partial = 0.0f;
  int beg = 0, end = 0;
  if (act) {
    beg = rowptr[n]; end = rowptr[n+1];
    acc = b2f(S[(size_t)n*64 + lane]);
    for (int p = beg; p < end; p++) {
      int e = perm[p];
      int vin = EI[e];
      int rel = EREL[e];
      acc += b2f(Y[(size_t)vin*448 + rel*64 + lane]);
    }
    int g = lane >> 4, k = lane & 15;
    for (int p = beg + g; p < end; p += 4) {
      int e = perm[p];
      partial += b2f(mo[(size_t)e*16 + k]);
    }
  }
  partial += __shfl_xor(partial, 16, 64);
  partial += __shfl_xor(partial, 32, 64);
  const float* Aupd = bn + 160;
  const float* Bupd = bn + 176;
  if (act && lane < 16) {
    float v = partial * deginv[n];
    u2s[w][lane] = fmaxf(v * Aupd[lane] + Bupd[lane], 0.0f);
  }
  __syncthreads();
  if (act) {
    float rel_out = fmaxf(acc, 0.0f);
    float ie = bl2[lane];
#pragma unroll
    for (int j = 0; j < 16; j++) ie += u2s[w][j] * Wl2[j*64 + lane];
    const float* Aout = bn + 192;
    const float* Bout = bn + 256;
    ie = ie * Aout[lane] + Bout[lane];
    float hidden = rel_out + ie + h[(size_t)n*64 + lane];
    float s = hidden;
#pragma unroll
    for (int off = 32; off > 0; off >>= 1) s += __shfl_xor(s, off, 64);
    float mu = s * (1.0f/64.0f);
    float d = hidden - mu;
    float s2 = d * d;
#pragma unroll
    for (int off = 32; off > 0; off >>= 1) s2 += __shfl_xor(s2, off, 64);
    float var = s2 * (1.0f/64.0f);
    float o = d * rsqrtf(var + 1e-5f) * lng[lane] + lnb[lane];
    hout[(size_t)n*64 + lane] = o;
  }
}

extern "C" void kernel_launch(void* const* d_in, const int* in_sizes, int n_in,
                              void* d_out, int out_size, void* d_ws, size_t ws_size,
                              hipStream_t stream) {
  const float* x    = (const float*)d_in[0];
  const float* posf = (const float*)d_in[1];
  const int* EI     = (const int*)d_in[2];
  const int* EREL   = (const int*)d_in[3];
  float* outf       = (float*)d_out;

  char* p = (char*)d_ws;
  auto alloc = [&](size_t bytes) -> char* {
    char* r = p;
    p += (bytes + 255) & ~((size_t)255);
    return r;
  };
  float* W      = (float*)alloc((size_t)135744 * 4);
  float* bnAB   = (float*)alloc((size_t)960 * 4);
  u16*   BswG   = (u16*)  alloc((size_t)3 * 8704 * 2);
  float* u      = (float*)alloc((size_t)Nn * 3 * 4);
  float* frame  = (float*)alloc((size_t)Nn * 9 * 4);
  int*   cnt    = (int*)  alloc((size_t)Nn * 4);
  int*   fill   = (int*)  alloc((size_t)Nn * 4);
  int*   rowptr = (int*)  alloc((size_t)(Nn + 1) * 4);
  int*   perm   = (int*)  alloc((size_t)Ne * 4);
  float* deginv = (float*)alloc((size_t)Nn * 4);
  float* h      = (float*)alloc((size_t)Nn * 64 * 4);
  u16*   S      = (u16*)  alloc((size_t)Nn * 64 * 2);
  u16*   Y      = (u16*)  alloc((size_t)Nn * 448 * 2);
  u16*   mo     = (u16*)  alloc((size_t)Ne * 16 * 2);
  (void)n_in; (void)in_sizes; (void)out_size;

  size_t needed = (size_t)(p - (char*)d_ws);
  if (needed > ws_size) return;  // diagnostic: zero output => absmax ~= max|ref|

  hipMemsetAsync(cnt,  0, (size_t)Nn * 4, stream);
  hipMemsetAsync(fill, 0, (size_t)Nn * 4, stream);

  for (int k = 0; k < 18; k++)
    hipMemcpyAsync(W + H_CUM[k], d_in[4 + k], (size_t)H_SZ[k] * 4,
                   hipMemcpyDeviceToDevice, stream);
  hipMemcpyAsync(h, x, (size_t)Nn * 64 * 4, hipMemcpyDeviceToDevice, stream);

  k_bnprep<<<2, 256, 0, stream>>>(W, bnAB);
  k_prep<<<(3*8704 + 255)/256, 256, 0, stream>>>(W, BswG);
  k_u<<<(Nn + 255)/256, 256, 0, stream>>>(posf, u);
  k_frame<<<(Nn + 255)/256, 256, 0, stream>>>(u, frame);
  k_cnt<<<Ne/256, 256, 0, stream>>>(EI, cnt);
  k_scan<<<1, 1024, 0, stream>>>(cnt, rowptr, deginv);
  k_place<<<Ne/256, 256, 0, stream>>>(EI, rowptr, fill, perm);

  for (int i = 0; i < Ll; i++) {
    const float* Wrel  = W + H_CUM[0]  + i * 28672;
    const float* brel  = W + H_CUM[1]  + i * 64;
    const float* Wself = W + H_CUM[2]  + i * 4096;
    const float* bself = W + H_CUM[3]  + i * 64;
    const float* Wl1   = W + H_CUM[4]  + i * 1024;
    const float* bl1   = W + H_CUM[5]  + i * 16;
    const float* Wk1   = W + H_CUM[6]  + i * 448;
    const float* bk1   = W + H_CUM[7]  + i * 32;
    const float* bk2   = W + H_CUM[9]  + i * 272;
    const float* Wl2   = W + H_CUM[10] + i * 1024;
    const float* bl2   = W + H_CUM[11] + i * 64;
    const float* lng   = W + H_CUM[16] + i * 64;
    const float* lnb   = W + H_CUM[17] + i * 64;
    const float* bnL   = bnAB + i * 320;
    const u16*   BswL  = BswG + i * 8704;

    k_rel<<<Nn/32, 256, 0, stream>>>(h, Wrel, Wself, brel, bself, Y, S);
    k_msg<<<Ne/256, 256, 0, stream>>>(h, posf, frame, EI, Wl1, bl1, Wk1, bk1,
                                      BswL, bk2, bnL, mo);
    k_node<<<(Nn + 3)/4, 256, 0, stream>>>(h, S, Y, rowptr, perm, EI, EREL, mo, deginv,
                                           Wl2, bl2, bnL, lng, lnb,
                                           (i == Ll - 1) ? outf : h);
  }
}

// Round 7
// 1366.505 us; speedup vs baseline: 3.3958x; 1.3227x over previous
//
#include <hip/hip_runtime.h>

typedef unsigned short u16;
typedef unsigned int   u32;

static const int Nn  = 100000;
static const int Ne  = 800000;
static const int Ll  = 3;
static const int SCAN_B = 98;  // ceil(100000/1024)

typedef short     short8  __attribute__((ext_vector_type(8)));
typedef float     floatx4 __attribute__((ext_vector_type(4)));

// ---- cumulative f32-weight offsets (inputs 4..21 concatenated into W) ----
static const int H_CUM[19] = {
  0, 86016, 86208, 98496, 98688, 101760, 101808, 103152, 103248,
  129360, 130176, 133248, 133440, 134208, 134400, 134592, 135360, 135552, 135744
};
static const int H_SZ[18] = {
  86016, 192, 12288, 192, 3072, 48, 1344, 96,
  26112, 816, 3072, 192, 768, 192, 192, 768, 192, 192
};

__device__ __forceinline__ float b2f(u16 v) {
  union { u32 u; float f; } x; x.u = ((u32)v) << 16; return x.f;
}
__device__ __forceinline__ u16 f2b(float f) {
  union { u32 u; float f; } x; x.f = f;
  u32 u = x.u;
  u32 r = (u + 0x7FFFu + ((u >> 16) & 1u)) >> 16;
  return (u16)r;
}

// ---- fold BN (eval) into A*x+B per layer; layout per layer (320 f32) ----
__global__ void k_bnprep(const float* __restrict__ W, float* __restrict__ bnAB) {
  int idx = blockIdx.x * blockDim.x + threadIdx.x;
  if (idx >= 480) return;
  int i = idx / 160, d0 = idx % 160;
  const float* src; float* dstA; float* dstB; int dim, d;
  if (d0 < 64)       { d = d0;      src = W + 133440 + i * 256; dim = 64; dstA = bnAB + i*320 + 0;   dstB = bnAB + i*320 + 64;  }
  else if (d0 < 80)  { d = d0 - 64; src = W + 134208 + i * 64;  dim = 16; dstA = bnAB + i*320 + 128; dstB = bnAB + i*320 + 144; }
  else if (d0 < 96)  { d = d0 - 80; src = W + 134400 + i * 64;  dim = 16; dstA = bnAB + i*320 + 160; dstB = bnAB + i*320 + 176; }
  else               { d = d0 - 96; src = W + 134592 + i * 256; dim = 64; dstA = bnAB + i*320 + 192; dstB = bnAB + i*320 + 256; }
  float g = src[0*dim+d], b = src[1*dim+d], m = src[2*dim+d], v = src[3*dim+d];
  float A = g * rsqrtf(v + 1e-5f);
  float B = b - m * A;
  dstA[d] = A; dstB[d] = B;
}

// ---- Bsw prep: B-fragment-ordered bf16 Wk2, K order flat = jp*32+q ----
__global__ void k_prep(const float* __restrict__ W, u16* __restrict__ BswG) {
  int i = blockIdx.x * 256 + threadIdx.x;
  if (i >= 3 * 8704) return;
  int layer = i / 8704, r = i % 8704;
  int jp = r / 512, l2 = r % 512;
  int lane = l2 / 8, j = l2 % 8;
  int q = (lane >> 4) * 8 + j, n = lane & 15;
  const float* Wk2 = W + 103248 + layer * 8704;
  BswG[i] = f2b(Wk2[q * 272 + jp * 16 + n]);
}

// ---- u[i] = normalize(pos[i]-pos[i-1]); u[0]=normalize(1,1,1) ----
__global__ void k_u(const float* __restrict__ posf, float* __restrict__ u) {
  int i = blockIdx.x * blockDim.x + threadIdx.x;
  if (i >= Nn) return;
  float ux, uy, uz;
  if (i == 0) { ux = uy = uz = 0.57735026918962584f; }
  else {
    float vx = posf[i*3+0] - posf[(i-1)*3+0];
    float vy = posf[i*3+1] - posf[(i-1)*3+1];
    float vz = posf[i*3+2] - posf[(i-1)*3+2];
    float nrm = sqrtf(vx*vx + vy*vy + vz*vz);
    float inv = 1.0f / fmaxf(nrm, 1e-12f);
    ux = vx*inv; uy = vy*inv; uz = vz*inv;
  }
  u[i*3+0] = ux; u[i*3+1] = uy; u[i*3+2] = uz;
}

// ---- frame[i] = [b, n, cross(b,n)] stored [j*3+k] ----
__global__ void k_frame(const float* __restrict__ u, float* __restrict__ frame) {
  int i = blockIdx.x * blockDim.x + threadIdx.x;
  if (i >= Nn) return;
  float bx, by, bz, nx, ny, nz;
  if (i < Nn - 1) {
    float ax = u[i*3+0], ay = u[i*3+1], az = u[i*3+2];
    float cx = u[(i+1)*3+0], cy = u[(i+1)*3+1], cz = u[(i+1)*3+2];
    float dx = ax-cx, dy = ay-cy, dz = az-cz;
    float n1 = sqrtf(dx*dx + dy*dy + dz*dz);
    float i1 = 1.0f / fmaxf(n1, 1e-12f);
    bx = dx*i1; by = dy*i1; bz = dz*i1;
    float qx = ay*cz - az*cy, qy = az*cx - ax*cz, qz = ax*cy - ay*cx;
    float n2 = sqrtf(qx*qx + qy*qy + qz*qz);
    float i2 = 1.0f / fmaxf(n2, 1e-12f);
    nx = qx*i2; ny = qy*i2; nz = qz*i2;
  } else {
    bx = by = bz = 0.57735026918962584f;
    nx = ny = nz = 0.57735026918962584f;
  }
  float ex = by*nz - bz*ny, ey = bz*nx - bx*nz, ez = bx*ny - by*nx;
  frame[i*9+0] = bx; frame[i*9+1] = nx; frame[i*9+2] = ex;
  frame[i*9+3] = by; frame[i*9+4] = ny; frame[i*9+5] = ey;
  frame[i*9+6] = bz; frame[i*9+7] = nz; frame[i*9+8] = ez;
}

// ---- degree count ----
__global__ void k_cnt(const int* __restrict__ EI, int* __restrict__ cnt) {
  int e = blockIdx.x * blockDim.x + threadIdx.x;
  if (e >= Ne) return;
  atomicAdd(&cnt[EI[Ne + e]], 1);
}

// ---- multi-block scan: stage 1 (per-block Hillis-Steele, 1024 elems) ----
__global__ __launch_bounds__(1024) void k_scan1(const int* __restrict__ cnt,
                                                int* __restrict__ locExc,
                                                int* __restrict__ btot) {
  __shared__ int sm[1024];
  int t = threadIdx.x, b = blockIdx.x;
  int i = b * 1024 + t;
  int v = (i < Nn) ? cnt[i] : 0;
  sm[t] = v;
  __syncthreads();
#pragma unroll
  for (int off = 1; off < 1024; off <<= 1) {
    int x = (t >= off) ? sm[t - off] : 0;
    __syncthreads();
    sm[t] += x;
    __syncthreads();
  }
  if (i < Nn) locExc[i] = sm[t] - v;
  if (t == 1023) btot[b] = sm[1023];
}

// ---- stage 2: serial scan of block totals (tiny) ----
__global__ void k_scan2(const int* __restrict__ btot, int* __restrict__ boff,
                        int* __restrict__ rowptr) {
  if (threadIdx.x != 0 || blockIdx.x != 0) return;
  int run = 0;
  for (int b = 0; b < SCAN_B; b++) { boff[b] = run; run += btot[b]; }
  rowptr[Nn] = run;
}

// ---- stage 3: combine + deginv ----
__global__ void k_scan3(const int* __restrict__ cnt, const int* __restrict__ locExc,
                        const int* __restrict__ boff, int* __restrict__ rowptr,
                        float* __restrict__ deginv) {
  int i = blockIdx.x * blockDim.x + threadIdx.x;
  if (i >= Nn) return;
  rowptr[i] = locExc[i] + boff[i >> 10];
  int dv = cnt[i] > 1 ? cnt[i] : 1;
  deginv[i] = 1.0f / (float)dv;
}

// ---- place: CSR-ordered Y-offsets + inverse permutation ----
__global__ void k_place(const int* __restrict__ EI, const int* __restrict__ EREL,
                        const int* __restrict__ rowptr,
                        int* __restrict__ fill, int* __restrict__ yidx,
                        int* __restrict__ inv) {
  int e = blockIdx.x * blockDim.x + threadIdx.x;
  if (e >= Ne) return;
  int vout = EI[Ne + e];
  int p = atomicAdd(&fill[vout], 1);
  int slot = rowptr[vout] + p;
  inv[e] = slot;
  yidx[slot] = EI[e] * 448 + EREL[e] * 64;
}

// ---- Y[n,r,k]; S[n,k] (both bf16) ----
__global__ __launch_bounds__(256) void k_rel(
    const float* __restrict__ h, const float* __restrict__ Wrel,
    const float* __restrict__ Wself, const float* __restrict__ brel,
    const float* __restrict__ bself, u16* __restrict__ Y, u16* __restrict__ S) {
  __shared__ float hs[32][64];
  int tid = threadIdx.x;
  int lane = tid & 63, w = tid >> 6;
  int nb0 = blockIdx.x * 32;
#pragma unroll
  for (int r = 0; r < 8; r++) {
    int idx = r * 256 + tid;
    int row = idx >> 6, col = idx & 63;
    int node = nb0 + row;
    hs[row][col] = (node < Nn) ? h[(size_t)node * 64 + col] : 0.0f;
  }
  __syncthreads();
  int base = w * 8;
  float bias = brel[lane] + bself[lane];
  float acc[8][8];
#pragma unroll
  for (int m = 0; m < 8; m++) {
#pragma unroll
    for (int r = 0; r < 7; r++) acc[m][r] = 0.0f;
    acc[m][7] = bias;
  }
  for (int c = 0; c < 64; c++) {
    float wv[8];
#pragma unroll
    for (int r = 0; r < 7; r++) wv[r] = Wrel[(r*64 + c)*64 + lane];
    wv[7] = Wself[c*64 + lane];
#pragma unroll
    for (int m = 0; m < 8; m++) {
      float hv = hs[base + m][c];
#pragma unroll
      for (int r = 0; r < 8; r++) acc[m][r] += hv * wv[r];
    }
  }
#pragma unroll
  for (int m = 0; m < 8; m++) {
    int node = nb0 + base + m;
    if (node >= Nn) continue;
#pragma unroll
    for (int r = 0; r < 7; r++) Y[(size_t)node*448 + r*64 + lane] = f2b(acc[m][r]);
    S[(size_t)node*64 + lane] = f2b(acc[m][7]);
  }
}

// ---- per-edge MFMA kernel (LDS-slim: a + z packed bf16 in one row of 56 u16) ----
__global__ __launch_bounds__(256) void k_msg(
    const float* __restrict__ h, const float* __restrict__ posf, const float* __restrict__ frame,
    const int* __restrict__ EI, const int* __restrict__ inv,
    const float* __restrict__ Wl1, const float* __restrict__ bl1,
    const float* __restrict__ Wk1, const float* __restrict__ bk1,
    const u16* __restrict__ BswG, const float* __restrict__ bk2,
    const float* __restrict__ bn, u16* __restrict__ mo) {
  __shared__ u16 abuf[256 * 56];  // [0:32)=a bf16, [32:48)=z bf16, pad to 56 (112 B row)
  __shared__ u32 bsw[4352];       // 17*64*8 bf16 B-fragments

  int tid = threadIdx.x;
  int e0 = blockIdx.x * 256;
  int e = e0 + tid;

  for (int i = tid; i < 4352; i += 256) bsw[i] = ((const u32*)BswG)[i];

  int vin = EI[e], vout = EI[Ne + e];

  // ---- m1 = relu(bn_msg(relu(bn_in(h[vin])) @ Wl1 + bl1)) ----
  const float* Ain = bn + 0;
  const float* Bin = bn + 64;
  float m1[16];
#pragma unroll
  for (int j = 0; j < 16; j++) m1[j] = bl1[j];
  const float4* hr = (const float4*)(h + (size_t)vin * 64);
  for (int c4 = 0; c4 < 16; c4++) {
    float4 hv = hr[c4];
    int c = c4 * 4;
    float l0 = fmaxf(hv.x * Ain[c+0] + Bin[c+0], 0.0f);
    float l1 = fmaxf(hv.y * Ain[c+1] + Bin[c+1], 0.0f);
    float l2 = fmaxf(hv.z * Ain[c+2] + Bin[c+2], 0.0f);
    float l3 = fmaxf(hv.w * Ain[c+3] + Bin[c+3], 0.0f);
#pragma unroll
    for (int j = 0; j < 16; j++)
      m1[j] += l0 * Wl1[(c+0)*16 + j] + l1 * Wl1[(c+1)*16 + j]
             + l2 * Wl1[(c+2)*16 + j] + l3 * Wl1[(c+3)*16 + j];
  }
  const float* Amsg = bn + 128;
  const float* Bmsg = bn + 144;
  u32* zr = (u32*)(abuf + (size_t)tid * 56 + 32);
#pragma unroll
  for (int j = 0; j < 8; j++) {
    u32 lo = f2b(fmaxf(m1[2*j]   * Amsg[2*j]   + Bmsg[2*j],   0.0f));
    u32 hi = f2b(fmaxf(m1[2*j+1] * Amsg[2*j+1] + Bmsg[2*j+1], 0.0f));
    zr[j] = lo | (hi << 16);
  }

  // ---- edge features + a = relu(ef @ Wk1 + bk1) ----
  float fi[9], fo[9];
#pragma unroll
  for (int t = 0; t < 9; t++) fi[t] = frame[(size_t)vin*9 + t];
#pragma unroll
  for (int t = 0; t < 9; t++) fo[t] = frame[(size_t)vout*9 + t];
  float d0 = posf[vout*3+0] - posf[vin*3+0];
  float d1 = posf[vout*3+1] - posf[vin*3+1];
  float d2 = posf[vout*3+2] - posf[vin*3+2];
  float ef[14];
#pragma unroll
  for (int k = 0; k < 3; k++) {
    ef[k]   = fi[0*3+k]*d0 + fi[1*3+k]*d1 + fi[2*3+k]*d2;
    ef[3+k] = fi[0*3+k]*fo[0*3+k] + fi[1*3+k]*fo[1*3+k] + fi[2*3+k]*fo[2*3+k];
  }
  int ad = vin - vout; if (ad < 0) ad = -ad;
  ef[6] = ((float)ad) / 6.0f;
#pragma unroll
  for (int k = 0; k < 7; k++) ef[7+k] = 1.0f - 2.0f*fabsf(ef[k]);

  float a[32];
#pragma unroll
  for (int q = 0; q < 32; q++) a[q] = bk1[q];
#pragma unroll
  for (int d = 0; d < 14; d++) {
    float fv = ef[d];
#pragma unroll
    for (int q = 0; q < 32; q++) a[q] += fv * Wk1[d*32 + q];
  }
  u32* ar = (u32*)(abuf + (size_t)tid * 56);
#pragma unroll
  for (int q = 0; q < 16; q++) {
    u32 lo = f2b(fmaxf(a[2*q],   0.0f));
    u32 hi = f2b(fmaxf(a[2*q+1], 0.0f));
    ar[q] = lo | (hi << 16);
  }
  __syncthreads();

  // ---- phase 2: MFMA ----
  int lane = tid & 63, w = tid >> 6;
  int m = lane & 15, quad = lane >> 4;
#pragma unroll
  for (int t = 0; t < 4; t++) {
    int s0 = (w * 4 + t) * 16;
    int s = s0 + m;
    union U { uint4 u; short8 v; u16 h[8]; };
    U afr;
    afr.u = *(const uint4*)(abuf + (size_t)s * 56 + quad * 8);
    float av[8];
#pragma unroll
    for (int j = 0; j < 8; j++) av[j] = b2f(afr.h[j]);

    floatx4 acc = {0.0f, 0.0f, 0.0f, 0.0f};
    U bfr;
    bfr.u = *(const uint4*)(bsw + (size_t)(0 * 64 + lane) * 4);
    acc = __builtin_amdgcn_mfma_f32_16x16x32_bf16(afr.v, bfr.v, acc, 0, 0, 0);

    const u16* zs = abuf + (size_t)s * 56 + 32;
#pragma unroll
    for (int jp = 1; jp < 17; jp++) {
      float zv = b2f(zs[jp - 1]);
      U pf;
#pragma unroll
      for (int j = 0; j < 4; j++) {
        u32 lo = f2b(av[2*j]   * zv);
        u32 hi = f2b(av[2*j+1] * zv);
        ((u32*)&pf.u)[j] = lo | (hi << 16);
      }
      bfr.u = *(const uint4*)(bsw + (size_t)(jp * 64 + lane) * 4);
      acc = __builtin_amdgcn_mfma_f32_16x16x32_bf16(pf.v, bfr.v, acc, 0, 0, 0);
    }

    // epilogue: lane holds D[row=quad*4+reg][col=k=lane&15]; store CSR-ordered via inv
    int k = m;
#pragma unroll
    for (int reg = 0; reg < 4; reg++) {
      int se = s0 + quad * 4 + reg;
      const u16* zz = abuf + (size_t)se * 56 + 32;
      float bias = bk2[k];
#pragma unroll
      for (int j = 0; j < 16; j++) bias += b2f(zz[j]) * bk2[(j + 1) * 16 + k];
      int slot = inv[e0 + se];
      mo[(size_t)slot * 16 + k] = f2b(acc[reg] + bias);
    }
  }
}

// ---- per-node: prefetched Y gather + sequential mo, residual, LN ----
__global__ __launch_bounds__(256) void k_node(
    const float* __restrict__ h, const u16* __restrict__ S, const u16* __restrict__ Y,
    const int* __restrict__ rowptr, const int* __restrict__ yidx,
    const u16* __restrict__ mo, const float* __restrict__ deginv,
    const float* __restrict__ Wl2, const float* __restrict__ bl2,
    const float* __restrict__ bn, const float* __restrict__ lng, const float* __restrict__ lnb,
    float* __restrict__ hout) {
  __shared__ float u2s[4][16];
  int tid = threadIdx.x;
  int lane = tid & 63, w = tid >> 6;
  int n = blockIdx.x * 4 + w;
  bool act = (n < Nn);

  float acc = 0.0f;
  float partial = 0.0f;
  if (act) {
    int beg = rowptr[n], end = rowptr[n+1];
    acc = b2f(S[(size_t)n*64 + lane]);
    for (int c0 = beg; c0 < end; c0 += 64) {
      int l = c0 + lane;
      int yo = (l < end) ? yidx[l] : 0;
      int cnt = end - c0; if (cnt > 64) cnt = 64;
      for (int j = 0; j < cnt; j++) {
        int yoj = __shfl(yo, j, 64);
        acc += b2f(Y[(size_t)yoj + lane]);
      }
    }
    int g = lane >> 4, k = lane & 15;
    for (int p = beg + g; p < end; p += 4)
      partial += b2f(mo[(size_t)p*16 + k]);
  }
  partial += __shfl_xor(partial, 16, 64);
  partial += __shfl_xor(partial, 32, 64);
  const float* Aupd = bn + 160;
  const float* Bupd = bn + 176;
  if (act && lane < 16) {
    float v = partial * deginv[n];
    u2s[w][lane] = fmaxf(v * Aupd[lane] + Bupd[lane], 0.0f);
  }
  __syncthreads();
  if (act) {
    float rel_out = fmaxf(acc, 0.0f);
    float ie = bl2[lane];
#pragma unroll
    for (int j = 0; j < 16; j++) ie += u2s[w][j] * Wl2[j*64 + lane];
    const float* Aout = bn + 192;
    const float* Bout = bn + 256;
    ie = ie * Aout[lane] + Bout[lane];
    float hidden = rel_out + ie + h[(size_t)n*64 + lane];
    float s = hidden;
#pragma unroll
    for (int off = 32; off > 0; off >>= 1) s += __shfl_xor(s, off, 64);
    float mu = s * (1.0f/64.0f);
    float d = hidden - mu;
    float s2 = d * d;
#pragma unroll
    for (int off = 32; off > 0; off >>= 1) s2 += __shfl_xor(s2, off, 64);
    float var = s2 * (1.0f/64.0f);
    float o = d * rsqrtf(var + 1e-5f) * lng[lane] + lnb[lane];
    hout[(size_t)n*64 + lane] = o;
  }
}

extern "C" void kernel_launch(void* const* d_in, const int* in_sizes, int n_in,
                              void* d_out, int out_size, void* d_ws, size_t ws_size,
                              hipStream_t stream) {
  const float* x    = (const float*)d_in[0];
  const float* posf = (const float*)d_in[1];
  const int* EI     = (const int*)d_in[2];
  const int* EREL   = (const int*)d_in[3];
  float* outf       = (float*)d_out;

  char* p = (char*)d_ws;
  auto alloc = [&](size_t bytes) -> char* {
    char* r = p;
    p += (bytes + 255) & ~((size_t)255);
    return r;
  };
  float* W      = (float*)alloc((size_t)135744 * 4);
  float* bnAB   = (float*)alloc((size_t)960 * 4);
  u16*   BswG   = (u16*)  alloc((size_t)3 * 8704 * 2);
  float* u      = (float*)alloc((size_t)Nn * 3 * 4);
  float* frame  = (float*)alloc((size_t)Nn * 9 * 4);
  int*   cnt    = (int*)  alloc((size_t)Nn * 4);
  int*   fill   = (int*)  alloc((size_t)Nn * 4);
  int*   rowptr = (int*)  alloc((size_t)(Nn + 1) * 4);
  int*   locExc = (int*)  alloc((size_t)Nn * 4);
  int*   btot   = (int*)  alloc((size_t)SCAN_B * 4);
  int*   boff   = (int*)  alloc((size_t)SCAN_B * 4);
  int*   yidx   = (int*)  alloc((size_t)Ne * 4);
  int*   inv    = (int*)  alloc((size_t)Ne * 4);
  float* deginv = (float*)alloc((size_t)Nn * 4);
  float* h      = (float*)alloc((size_t)Nn * 64 * 4);
  u16*   S      = (u16*)  alloc((size_t)Nn * 64 * 2);
  u16*   Y      = (u16*)  alloc((size_t)Nn * 448 * 2);
  u16*   mo     = (u16*)  alloc((size_t)Ne * 16 * 2);
  (void)n_in; (void)in_sizes; (void)out_size;

  size_t needed = (size_t)(p - (char*)d_ws);
  if (needed > ws_size) return;  // diagnostic: zero output => absmax ~= max|ref|

  hipMemsetAsync(cnt,  0, (size_t)Nn * 4, stream);
  hipMemsetAsync(fill, 0, (size_t)Nn * 4, stream);

  for (int k = 0; k < 18; k++)
    hipMemcpyAsync(W + H_CUM[k], d_in[4 + k], (size_t)H_SZ[k] * 4,
                   hipMemcpyDeviceToDevice, stream);
  hipMemcpyAsync(h, x, (size_t)Nn * 64 * 4, hipMemcpyDeviceToDevice, stream);

  k_bnprep<<<2, 256, 0, stream>>>(W, bnAB);
  k_prep<<<(3*8704 + 255)/256, 256, 0, stream>>>(W, BswG);
  k_u<<<(Nn + 255)/256, 256, 0, stream>>>(posf, u);
  k_frame<<<(Nn + 255)/256, 256, 0, stream>>>(u, frame);
  k_cnt<<<Ne/256, 256, 0, stream>>>(EI, cnt);
  k_scan1<<<SCAN_B, 1024, 0, stream>>>(cnt, locExc, btot);
  k_scan2<<<1, 64, 0, stream>>>(btot, boff, rowptr);
  k_scan3<<<(Nn + 255)/256, 256, 0, stream>>>(cnt, locExc, boff, rowptr, deginv);
  k_place<<<Ne/256, 256, 0, stream>>>(EI, EREL, rowptr, fill, yidx, inv);

  for (int i = 0; i < Ll; i++) {
    const float* Wrel  = W + H_CUM[0]  + i * 28672;
    const float* brel  = W + H_CUM[1]  + i * 64;
    const float* Wself = W + H_CUM[2]  + i * 4096;
    const float* bself = W + H_CUM[3]  + i * 64;
    const float* Wl1   = W + H_CUM[4]  + i * 1024;
    const float* bl1   = W + H_CUM[5]  + i * 16;
    const float* Wk1   = W + H_CUM[6]  + i * 448;
    const float* bk1   = W + H_CUM[7]  + i * 32;
    const float* bk2   = W + H_CUM[9]  + i * 272;
    const float* Wl2   = W + H_CUM[10] + i * 1024;
    const float* bl2   = W + H_CUM[11] + i * 64;
    const float* lng   = W + H_CUM[16] + i * 64;
    const float* lnb   = W + H_CUM[17] + i * 64;
    const float* bnL   = bnAB + i * 320;
    const u16*   BswL  = BswG + i * 8704;

    k_rel<<<Nn/32, 256, 0, stream>>>(h, Wrel, Wself, brel, bself, Y, S);
    k_msg<<<Ne/256, 256, 0, stream>>>(h, posf, frame, EI, inv, Wl1, bl1, Wk1, bk1,
                                      BswL, bk2, bnL, mo);
    k_node<<<(Nn + 3)/4, 256, 0, stream>>>(h, S, Y, rowptr, yidx, mo, deginv,
                                           Wl2, bl2, bnL, lng, lnb,
                                           (i == Ll - 1) ? outf : h);
  }
}

// Round 8
// 1272.721 us; speedup vs baseline: 3.6461x; 1.0737x over previous
//
#include <hip/hip_runtime.h>
#include <hip/hip_bf16.h>

typedef unsigned short u16;
typedef unsigned int   u32;

static const int Nn  = 100000;
static const int Ne  = 800000;
static const int Ll  = 3;
static const int SCAN_B = 98;  // ceil(100000/1024)

typedef short     short8  __attribute__((ext_vector_type(8)));
typedef float     floatx4 __attribute__((ext_vector_type(4)));

// ---- cumulative f32-weight offsets (inputs 4..21 concatenated into W) ----
static const int H_CUM[19] = {
  0, 86016, 86208, 98496, 98688, 101760, 101808, 103152, 103248,
  129360, 130176, 133248, 133440, 134208, 134400, 134592, 135360, 135552, 135744
};
static const int H_SZ[18] = {
  86016, 192, 12288, 192, 3072, 48, 1344, 96,
  26112, 816, 3072, 192, 768, 192, 192, 768, 192, 192
};

union FU { u32 u; float f; };
__device__ __forceinline__ float b2f(u16 v) { FU x; x.u = ((u32)v) << 16; return x.f; }
__device__ __forceinline__ float lo2f(u32 w) { FU x; x.u = w << 16; return x.f; }
__device__ __forceinline__ float hi2f(u32 w) { FU x; x.u = w & 0xffff0000u; return x.f; }
__device__ __forceinline__ u16 f2b(float f) {
  FU x; x.f = f;
  u32 u = x.u;
  u32 r = (u + 0x7FFFu + ((u >> 16) & 1u)) >> 16;
  return (u16)r;
}
// packed f32x2 -> bf16x2 (v_cvt_pk_bf16_f32 on gfx950; RNE)
__device__ __forceinline__ u32 pk2(float a, float b) {
  __hip_bfloat162 h2 = __float22bfloat162_rn(make_float2(a, b));
  union { __hip_bfloat162 h; u32 u; } c; c.h = h2; return c.u;
}

// ---- fold BN (eval) into A*x+B per layer; layout per layer (320 f32) ----
__global__ void k_bnprep(const float* __restrict__ W, float* __restrict__ bnAB) {
  int idx = blockIdx.x * blockDim.x + threadIdx.x;
  if (idx >= 480) return;
  int i = idx / 160, d0 = idx % 160;
  const float* src; float* dstA; float* dstB; int dim, d;
  if (d0 < 64)       { d = d0;      src = W + 133440 + i * 256; dim = 64; dstA = bnAB + i*320 + 0;   dstB = bnAB + i*320 + 64;  }
  else if (d0 < 80)  { d = d0 - 64; src = W + 134208 + i * 64;  dim = 16; dstA = bnAB + i*320 + 128; dstB = bnAB + i*320 + 144; }
  else if (d0 < 96)  { d = d0 - 80; src = W + 134400 + i * 64;  dim = 16; dstA = bnAB + i*320 + 160; dstB = bnAB + i*320 + 176; }
  else               { d = d0 - 96; src = W + 134592 + i * 256; dim = 64; dstA = bnAB + i*320 + 192; dstB = bnAB + i*320 + 256; }
  float g = src[0*dim+d], b = src[1*dim+d], m = src[2*dim+d], v = src[3*dim+d];
  float A = g * rsqrtf(v + 1e-5f);
  float B = b - m * A;
  dstA[d] = A; dstB[d] = B;
}

// ---- Bsw prep: B-fragment-ordered bf16 Wk2, K order flat = jp*32+q ----
__global__ void k_prep(const float* __restrict__ W, u16* __restrict__ BswG) {
  int i = blockIdx.x * 256 + threadIdx.x;
  if (i >= 3 * 8704) return;
  int layer = i / 8704, r = i % 8704;
  int jp = r / 512, l2 = r % 512;
  int lane = l2 / 8, j = l2 % 8;
  int q = (lane >> 4) * 8 + j, n = lane & 15;
  const float* Wk2 = W + 103248 + layer * 8704;
  BswG[i] = f2b(Wk2[q * 272 + jp * 16 + n]);
}

// ---- u[i] = normalize(pos[i]-pos[i-1]) ----
__global__ void k_u(const float* __restrict__ posf, float* __restrict__ u) {
  int i = blockIdx.x * blockDim.x + threadIdx.x;
  if (i >= Nn) return;
  float ux, uy, uz;
  if (i == 0) { ux = uy = uz = 0.57735026918962584f; }
  else {
    float vx = posf[i*3+0] - posf[(i-1)*3+0];
    float vy = posf[i*3+1] - posf[(i-1)*3+1];
    float vz = posf[i*3+2] - posf[(i-1)*3+2];
    float nrm = sqrtf(vx*vx + vy*vy + vz*vz);
    float inv = 1.0f / fmaxf(nrm, 1e-12f);
    ux = vx*inv; uy = vy*inv; uz = vz*inv;
  }
  u[i*3+0] = ux; u[i*3+1] = uy; u[i*3+2] = uz;
}

// ---- frame[i] = [b, n, cross(b,n)] stored [j*3+k] ----
__global__ void k_frame(const float* __restrict__ u, float* __restrict__ frame) {
  int i = blockIdx.x * blockDim.x + threadIdx.x;
  if (i >= Nn) return;
  float bx, by, bz, nx, ny, nz;
  if (i < Nn - 1) {
    float ax = u[i*3+0], ay = u[i*3+1], az = u[i*3+2];
    float cx = u[(i+1)*3+0], cy = u[(i+1)*3+1], cz = u[(i+1)*3+2];
    float dx = ax-cx, dy = ay-cy, dz = az-cz;
    float n1 = sqrtf(dx*dx + dy*dy + dz*dz);
    float i1 = 1.0f / fmaxf(n1, 1e-12f);
    bx = dx*i1; by = dy*i1; bz = dz*i1;
    float qx = ay*cz - az*cy, qy = az*cx - ax*cz, qz = ax*cy - ay*cx;
    float n2 = sqrtf(qx*qx + qy*qy + qz*qz);
    float i2 = 1.0f / fmaxf(n2, 1e-12f);
    nx = qx*i2; ny = qy*i2; nz = qz*i2;
  } else {
    bx = by = bz = 0.57735026918962584f;
    nx = ny = nz = 0.57735026918962584f;
  }
  float ex = by*nz - bz*ny, ey = bz*nx - bx*nz, ez = bx*ny - by*nx;
  frame[i*9+0] = bx; frame[i*9+1] = nx; frame[i*9+2] = ex;
  frame[i*9+3] = by; frame[i*9+4] = ny; frame[i*9+5] = ey;
  frame[i*9+6] = bz; frame[i*9+7] = nz; frame[i*9+8] = ez;
}

// ---- degree count ----
__global__ void k_cnt(const int* __restrict__ EI, int* __restrict__ cnt) {
  int e = blockIdx.x * blockDim.x + threadIdx.x;
  if (e >= Ne) return;
  atomicAdd(&cnt[EI[Ne + e]], 1);
}

// ---- multi-block scan ----
__global__ __launch_bounds__(1024) void k_scan1(const int* __restrict__ cnt,
                                                int* __restrict__ locExc,
                                                int* __restrict__ btot) {
  __shared__ int sm[1024];
  int t = threadIdx.x, b = blockIdx.x;
  int i = b * 1024 + t;
  int v = (i < Nn) ? cnt[i] : 0;
  sm[t] = v;
  __syncthreads();
#pragma unroll
  for (int off = 1; off < 1024; off <<= 1) {
    int x = (t >= off) ? sm[t - off] : 0;
    __syncthreads();
    sm[t] += x;
    __syncthreads();
  }
  if (i < Nn) locExc[i] = sm[t] - v;
  if (t == 1023) btot[b] = sm[1023];
}

__global__ void k_scan2(const int* __restrict__ btot, int* __restrict__ boff,
                        int* __restrict__ rowptr) {
  if (threadIdx.x != 0 || blockIdx.x != 0) return;
  int run = 0;
  for (int b = 0; b < SCAN_B; b++) { boff[b] = run; run += btot[b]; }
  rowptr[Nn] = run;
}

__global__ void k_scan3(const int* __restrict__ cnt, const int* __restrict__ locExc,
                        const int* __restrict__ boff, int* __restrict__ rowptr,
                        float* __restrict__ deginv) {
  int i = blockIdx.x * blockDim.x + threadIdx.x;
  if (i >= Nn) return;
  rowptr[i] = locExc[i] + boff[i >> 10];
  int dv = cnt[i] > 1 ? cnt[i] : 1;
  deginv[i] = 1.0f / (float)dv;
}

// ---- place: CSR-ordered Y-offsets + inverse permutation ----
__global__ void k_place(const int* __restrict__ EI, const int* __restrict__ EREL,
                        const int* __restrict__ rowptr,
                        int* __restrict__ fill, int* __restrict__ yidx,
                        int* __restrict__ inv) {
  int e = blockIdx.x * blockDim.x + threadIdx.x;
  if (e >= Ne) return;
  int vout = EI[Ne + e];
  int p = atomicAdd(&fill[vout], 1);
  int slot = rowptr[vout] + p;
  inv[e] = slot;
  yidx[slot] = EI[e] * 448 + EREL[e] * 64;
}

// ---- Y[n,r,k]; S[n,k] (both bf16) ----
__global__ __launch_bounds__(256) void k_rel(
    const float* __restrict__ h, const float* __restrict__ Wrel,
    const float* __restrict__ Wself, const float* __restrict__ brel,
    const float* __restrict__ bself, u16* __restrict__ Y, u16* __restrict__ S) {
  __shared__ float hs[32][64];
  int tid = threadIdx.x;
  int lane = tid & 63, w = tid >> 6;
  int nb0 = blockIdx.x * 32;
#pragma unroll
  for (int r = 0; r < 8; r++) {
    int idx = r * 256 + tid;
    int row = idx >> 6, col = idx & 63;
    int node = nb0 + row;
    hs[row][col] = (node < Nn) ? h[(size_t)node * 64 + col] : 0.0f;
  }
  __syncthreads();
  int base = w * 8;
  float bias = brel[lane] + bself[lane];
  float acc[8][8];
#pragma unroll
  for (int m = 0; m < 8; m++) {
#pragma unroll
    for (int r = 0; r < 7; r++) acc[m][r] = 0.0f;
    acc[m][7] = bias;
  }
  for (int c = 0; c < 64; c++) {
    float wv[8];
#pragma unroll
    for (int r = 0; r < 7; r++) wv[r] = Wrel[(r*64 + c)*64 + lane];
    wv[7] = Wself[c*64 + lane];
#pragma unroll
    for (int m = 0; m < 8; m++) {
      float hv = hs[base + m][c];
#pragma unroll
      for (int r = 0; r < 8; r++) acc[m][r] += hv * wv[r];
    }
  }
#pragma unroll
  for (int m = 0; m < 8; m++) {
    int node = nb0 + base + m;
    if (node >= Nn) continue;
#pragma unroll
    for (int r = 0; r < 7; r++) Y[(size_t)node*448 + r*64 + lane] = f2b(acc[m][r]);
    S[(size_t)node*64 + lane] = f2b(acc[m][7]);
  }
}

// ---- per-node z + bias precompute:
// z[n] = relu(bn_msg(relu(bn_in(h[n])) @ Wl1 + bl1))  (16 bf16)
// bias[n,k] = bk2[0,k] + sum_j z_j bk2[j+1,k]         (16 bf16) ----
__global__ __launch_bounds__(256) void k_z(
    const float* __restrict__ h, const float* __restrict__ Wl1, const float* __restrict__ bl1,
    const float* __restrict__ bk2, const float* __restrict__ bn,
    u16* __restrict__ zt, u16* __restrict__ biast) {
  __shared__ float ls[64][65];
  __shared__ float zz[64][17];
  int tid = threadIdx.x;
  int nb0 = blockIdx.x * 64;
  const float* Ain = bn + 0;
  const float* Bin = bn + 64;
#pragma unroll
  for (int r = 0; r < 16; r++) {
    int idx = r * 256 + tid;
    int row = idx >> 6, col = idx & 63;
    int node = nb0 + row;
    float v = (node < Nn) ? h[(size_t)node * 64 + col] : 0.0f;
    ls[row][col] = fmaxf(v * Ain[col] + Bin[col], 0.0f);
  }
  __syncthreads();
  int row = tid >> 2, jq = (tid & 3) * 4;
  int node = nb0 + row;
  const float* Amsg = bn + 128;
  const float* Bmsg = bn + 144;
  float m1[4];
#pragma unroll
  for (int t = 0; t < 4; t++) m1[t] = bl1[jq + t];
  for (int c = 0; c < 64; c++) {
    float lv = ls[row][c];
#pragma unroll
    for (int t = 0; t < 4; t++) m1[t] += lv * Wl1[c * 16 + jq + t];
  }
  float zv[4];
#pragma unroll
  for (int t = 0; t < 4; t++) {
    zv[t] = fmaxf(m1[t] * Amsg[jq + t] + Bmsg[jq + t], 0.0f);
    zz[row][jq + t] = zv[t];
  }
  if (node < Nn) {
    u32* zg = (u32*)zt + (size_t)node * 8 + (tid & 3) * 2;
    zg[0] = pk2(zv[0], zv[1]);
    zg[1] = pk2(zv[2], zv[3]);
  }
  __syncthreads();
  float bb[4];
#pragma unroll
  for (int t = 0; t < 4; t++) bb[t] = bk2[jq + t];
  for (int j = 0; j < 16; j++) {
    float zj = zz[row][j];
#pragma unroll
    for (int t = 0; t < 4; t++) bb[t] += zj * bk2[(j + 1) * 16 + jq + t];
  }
  if (node < Nn) {
    u32* bg = (u32*)biast + (size_t)node * 8 + (tid & 3) * 2;
    bg[0] = pk2(bb[0], bb[1]);
    bg[1] = pk2(bb[2], bb[3]);
  }
}

// ---- per-edge MFMA kernel (z/bias gathered, 3 blocks/CU) ----
__global__ __launch_bounds__(256) void k_msg(
    const float* __restrict__ posf, const float* __restrict__ frame,
    const int* __restrict__ EI, const int* __restrict__ inv,
    const u16* __restrict__ zt, const u16* __restrict__ biast,
    const float* __restrict__ Wk1, const float* __restrict__ bk1,
    const u16* __restrict__ BswG, u16* __restrict__ mo) {
  // row = 72 u16 (144 B): a[0:32] | z[32:48] | bias[48:64] | pad[64:72]
  __shared__ u16 abuf[256 * 72];   // 36864 B
  __shared__ u32 bsw[4352];        // 17408 B  (total 54272 B -> 3 blocks/CU)

  int tid = threadIdx.x;
  int e0 = blockIdx.x * 256;
  int e = e0 + tid;

  for (int i = tid; i < 4352; i += 256) bsw[i] = ((const u32*)BswG)[i];

  int vin = EI[e], vout = EI[Ne + e];

  // ---- gather z/bias (bf16, 32 B each) into LDS row ----
  {
    const uint4* zg = (const uint4*)(zt + (size_t)vin * 16);
    uint4* zr = (uint4*)(abuf + (size_t)tid * 72 + 32);
    zr[0] = zg[0]; zr[1] = zg[1];
    const uint4* bg = (const uint4*)(biast + (size_t)vin * 16);
    uint4* br = (uint4*)(abuf + (size_t)tid * 72 + 48);
    br[0] = bg[0]; br[1] = bg[1];
  }

  // ---- edge features + a = relu(ef @ Wk1 + bk1) ----
  float fi[9], fo[9];
#pragma unroll
  for (int t = 0; t < 9; t++) fi[t] = frame[(size_t)vin*9 + t];
#pragma unroll
  for (int t = 0; t < 9; t++) fo[t] = frame[(size_t)vout*9 + t];
  float d0 = posf[vout*3+0] - posf[vin*3+0];
  float d1 = posf[vout*3+1] - posf[vin*3+1];
  float d2 = posf[vout*3+2] - posf[vin*3+2];
  float ef[14];
#pragma unroll
  for (int k = 0; k < 3; k++) {
    ef[k]   = fi[0*3+k]*d0 + fi[1*3+k]*d1 + fi[2*3+k]*d2;
    ef[3+k] = fi[0*3+k]*fo[0*3+k] + fi[1*3+k]*fo[1*3+k] + fi[2*3+k]*fo[2*3+k];
  }
  int ad = vin - vout; if (ad < 0) ad = -ad;
  ef[6] = ((float)ad) / 6.0f;
#pragma unroll
  for (int k = 0; k < 7; k++) ef[7+k] = 1.0f - 2.0f*fabsf(ef[k]);

  float a[32];
#pragma unroll
  for (int q = 0; q < 32; q++) a[q] = bk1[q];
#pragma unroll
  for (int d = 0; d < 14; d++) {
    float fv = ef[d];
#pragma unroll
    for (int q = 0; q < 32; q++) a[q] += fv * Wk1[d*32 + q];
  }
  u32* ar = (u32*)(abuf + (size_t)tid * 72);
#pragma unroll
  for (int q = 0; q < 16; q++)
    ar[q] = pk2(fmaxf(a[2*q], 0.0f), fmaxf(a[2*q+1], 0.0f));
  __syncthreads();

  // ---- phase 2: 17 MFMAs per 16-edge tile ----
  int lane = tid & 63, w4 = (tid >> 6) * 4;
  int m = lane & 15, quad = lane >> 4;
  union U { uint4 u; short8 v; };
#pragma unroll
  for (int t = 0; t < 4; t++) {
    int s0 = (w4 + t) * 16;
    int s = s0 + m;
    const u16* rs = abuf + (size_t)s * 72;
    U afr;
    afr.u = *(const uint4*)(rs + quad * 8);
    const u32* aw = (const u32*)&afr.u;
    float av[8];
#pragma unroll
    for (int j = 0; j < 4; j++) { av[2*j] = lo2f(aw[j]); av[2*j+1] = hi2f(aw[j]); }

    uint4 zu0 = *(const uint4*)(rs + 32);
    uint4 zu1 = *(const uint4*)(rs + 40);
    const u32* zw0 = (const u32*)&zu0;
    const u32* zw1 = (const u32*)&zu1;
    float zf[16];
#pragma unroll
    for (int j = 0; j < 4; j++) {
      zf[2*j]   = lo2f(zw0[j]); zf[2*j+1]   = hi2f(zw0[j]);
      zf[8+2*j] = lo2f(zw1[j]); zf[8+2*j+1] = hi2f(zw1[j]);
    }

    floatx4 acc = {0.0f, 0.0f, 0.0f, 0.0f};
    U bfr;
    bfr.u = *(const uint4*)(bsw + (size_t)(0 * 64 + lane) * 4);
    acc = __builtin_amdgcn_mfma_f32_16x16x32_bf16(afr.v, bfr.v, acc, 0, 0, 0);

#pragma unroll
    for (int jp = 1; jp < 17; jp++) {
      float zv = zf[jp - 1];
      U pf;
      u32* pw = (u32*)&pf.u;
#pragma unroll
      for (int j = 0; j < 4; j++)
        pw[j] = pk2(av[2*j] * zv, av[2*j+1] * zv);
      bfr.u = *(const uint4*)(bsw + (size_t)(jp * 64 + lane) * 4);
      acc = __builtin_amdgcn_mfma_f32_16x16x32_bf16(pf.v, bfr.v, acc, 0, 0, 0);
    }

    // epilogue: lane holds D[row=quad*4+reg][col=k=lane&15]
    int k = m;
#pragma unroll
    for (int reg = 0; reg < 4; reg++) {
      int se = s0 + quad * 4 + reg;
      float bias = b2f(abuf[(size_t)se * 72 + 48 + k]);
      int slot = inv[e0 + se];
      mo[(size_t)slot * 16 + k] = f2b(acc[reg] + bias);
    }
  }
}

// ---- per-node: prefetched Y gather + sequential mo, residual, LN ----
__global__ __launch_bounds__(256) void k_node(
    const float* __restrict__ h, const u16* __restrict__ S, const u16* __restrict__ Y,
    const int* __restrict__ rowptr, const int* __restrict__ yidx,
    const u16* __restrict__ mo, const float* __restrict__ deginv,
    const float* __restrict__ Wl2, const float* __restrict__ bl2,
    const float* __restrict__ bn, const float* __restrict__ lng, const float* __restrict__ lnb,
    float* __restrict__ hout) {
  __shared__ float u2s[4][16];
  int tid = threadIdx.x;
  int lane = tid & 63, w = tid >> 6;
  int n = blockIdx.x * 4 + w;
  bool act = (n < Nn);

  float acc = 0.0f;
  float partial = 0.0f;
  if (act) {
    int beg = rowptr[n], end = rowptr[n+1];
    acc = b2f(S[(size_t)n*64 + lane]);
    for (int c0 = beg; c0 < end; c0 += 64) {
      int l = c0 + lane;
      int yo = (l < end) ? yidx[l] : 0;
      int cnt = end - c0; if (cnt > 64) cnt = 64;
      for (int j = 0; j < cnt; j++) {
        int yoj = __shfl(yo, j, 64);
        acc += b2f(Y[(size_t)yoj + lane]);
      }
    }
    int g = lane >> 4, k = lane & 15;
    for (int p = beg + g; p < end; p += 4)
      partial += b2f(mo[(size_t)p*16 + k]);
  }
  partial += __shfl_xor(partial, 16, 64);
  partial += __shfl_xor(partial, 32, 64);
  const float* Aupd = bn + 160;
  const float* Bupd = bn + 176;
  if (act && lane < 16) {
    float v = partial * deginv[n];
    u2s[w][lane] = fmaxf(v * Aupd[lane] + Bupd[lane], 0.0f);
  }
  __syncthreads();
  if (act) {
    float rel_out = fmaxf(acc, 0.0f);
    float ie = bl2[lane];
#pragma unroll
    for (int j = 0; j < 16; j++) ie += u2s[w][j] * Wl2[j*64 + lane];
    const float* Aout = bn + 192;
    const float* Bout = bn + 256;
    ie = ie * Aout[lane] + Bout[lane];
    float hidden = rel_out + ie + h[(size_t)n*64 + lane];
    float s = hidden;
#pragma unroll
    for (int off = 32; off > 0; off >>= 1) s += __shfl_xor(s, off, 64);
    float mu = s * (1.0f/64.0f);
    float d = hidden - mu;
    float s2 = d * d;
#pragma unroll
    for (int off = 32; off > 0; off >>= 1) s2 += __shfl_xor(s2, off, 64);
    float var = s2 * (1.0f/64.0f);
    float o = d * rsqrtf(var + 1e-5f) * lng[lane] + lnb[lane];
    hout[(size_t)n*64 + lane] = o;
  }
}

extern "C" void kernel_launch(void* const* d_in, const int* in_sizes, int n_in,
                              void* d_out, int out_size, void* d_ws, size_t ws_size,
                              hipStream_t stream) {
  const float* x    = (const float*)d_in[0];
  const float* posf = (const float*)d_in[1];
  const int* EI     = (const int*)d_in[2];
  const int* EREL   = (const int*)d_in[3];
  float* outf       = (float*)d_out;

  char* p = (char*)d_ws;
  auto alloc = [&](size_t bytes) -> char* {
    char* r = p;
    p += (bytes + 255) & ~((size_t)255);
    return r;
  };
  float* W      = (float*)alloc((size_t)135744 * 4);
  float* bnAB   = (float*)alloc((size_t)960 * 4);
  u16*   BswG   = (u16*)  alloc((size_t)3 * 8704 * 2);
  float* u      = (float*)alloc((size_t)Nn * 3 * 4);
  float* frame  = (float*)alloc((size_t)Nn * 9 * 4);
  int*   cnt    = (int*)  alloc((size_t)Nn * 4);
  int*   fill   = (int*)  alloc((size_t)Nn * 4);
  int*   rowptr = (int*)  alloc((size_t)(Nn + 1) * 4);
  int*   locExc = (int*)  alloc((size_t)Nn * 4);
  int*   btot   = (int*)  alloc((size_t)SCAN_B * 4);
  int*   boff   = (int*)  alloc((size_t)SCAN_B * 4);
  int*   yidx   = (int*)  alloc((size_t)Ne * 4);
  int*   inv    = (int*)  alloc((size_t)Ne * 4);
  float* deginv = (float*)alloc((size_t)Nn * 4);
  float* h      = (float*)alloc((size_t)Nn * 64 * 4);
  u16*   S      = (u16*)  alloc((size_t)Nn * 64 * 2);
  u16*   Y      = (u16*)  alloc((size_t)Nn * 448 * 2);
  u16*   mo     = (u16*)  alloc((size_t)Ne * 16 * 2);
  u16*   zt     = (u16*)  alloc((size_t)Nn * 16 * 2);
  u16*   biast  = (u16*)  alloc((size_t)Nn * 16 * 2);
  (void)n_in; (void)in_sizes; (void)out_size;

  size_t needed = (size_t)(p - (char*)d_ws);
  if (needed > ws_size) return;  // diagnostic: zero output => absmax ~= max|ref|

  hipMemsetAsync(cnt,  0, (size_t)Nn * 4, stream);
  hipMemsetAsync(fill, 0, (size_t)Nn * 4, stream);

  for (int k = 0; k < 18; k++)
    hipMemcpyAsync(W + H_CUM[k], d_in[4 + k], (size_t)H_SZ[k] * 4,
                   hipMemcpyDeviceToDevice, stream);
  hipMemcpyAsync(h, x, (size_t)Nn * 64 * 4, hipMemcpyDeviceToDevice, stream);

  k_bnprep<<<2, 256, 0, stream>>>(W, bnAB);
  k_prep<<<(3*8704 + 255)/256, 256, 0, stream>>>(W, BswG);
  k_u<<<(Nn + 255)/256, 256, 0, stream>>>(posf, u);
  k_frame<<<(Nn + 255)/256, 256, 0, stream>>>(u, frame);
  k_cnt<<<Ne/256, 256, 0, stream>>>(EI, cnt);
  k_scan1<<<SCAN_B, 1024, 0, stream>>>(cnt, locExc, btot);
  k_scan2<<<1, 64, 0, stream>>>(btot, boff, rowptr);
  k_scan3<<<(Nn + 255)/256, 256, 0, stream>>>(cnt, locExc, boff, rowptr, deginv);
  k_place<<<Ne/256, 256, 0, stream>>>(EI, EREL, rowptr, fill, yidx, inv);

  for (int i = 0; i < Ll; i++) {
    const float* Wrel  = W + H_CUM[0]  + i * 28672;
    const float* brel  = W + H_CUM[1]  + i * 64;
    const float* Wself = W + H_CUM[2]  + i * 4096;
    const float* bself = W + H_CUM[3]  + i * 64;
    const float* Wl1   = W + H_CUM[4]  + i * 1024;
    const float* bl1   = W + H_CUM[5]  + i * 16;
    const float* Wk1   = W + H_CUM[6]  + i * 448;
    const float* bk1   = W + H_CUM[7]  + i * 32;
    const float* bk2   = W + H_CUM[9]  + i * 272;
    const float* Wl2   = W + H_CUM[10] + i * 1024;
    const float* bl2   = W + H_CUM[11] + i * 64;
    const float* lng   = W + H_CUM[16] + i * 64;
    const float* lnb   = W + H_CUM[17] + i * 64;
    const float* bnL   = bnAB + i * 320;
    const u16*   BswL  = BswG + i * 8704;

    k_rel<<<Nn/32, 256, 0, stream>>>(h, Wrel, Wself, brel, bself, Y, S);
    k_z<<<(Nn + 63)/64, 256, 0, stream>>>(h, Wl1, bl1, bk2, bnL, zt, biast);
    k_msg<<<Ne/256, 256, 0, stream>>>(posf, frame, EI, inv, zt, biast, Wk1, bk1,
                                      BswL, mo);
    k_node<<<(Nn + 3)/4, 256, 0, stream>>>(h, S, Y, rowptr, yidx, mo, deginv,
                                           Wl2, bl2, bnL, lng, lnb,
                                           (i == Ll - 1) ? outf : h);
  }
}

// Round 10
// 1191.926 us; speedup vs baseline: 3.8932x; 1.0678x over previous
//
#include <hip/hip_runtime.h>
#include <hip/hip_bf16.h>

typedef unsigned short u16;
typedef unsigned int   u32;

static const int Nn  = 100000;
static const int Ne  = 800000;
static const int Ll  = 3;
static const int SCAN_B = 98;  // ceil(100000/1024)

typedef short     short8  __attribute__((ext_vector_type(8)));
typedef float     floatx4 __attribute__((ext_vector_type(4)));

// ---- cumulative f32-weight offsets (inputs 4..21 concatenated into W) ----
static const int H_CUM[19] = {
  0, 86016, 86208, 98496, 98688, 101760, 101808, 103152, 103248,
  129360, 130176, 133248, 133440, 134208, 134400, 134592, 135360, 135552, 135744
};
static const int H_SZ[18] = {
  86016, 192, 12288, 192, 3072, 48, 1344, 96,
  26112, 816, 3072, 192, 768, 192, 192, 768, 192, 192
};

union FU { u32 u; float f; };
__device__ __forceinline__ float b2f(u16 v) { FU x; x.u = ((u32)v) << 16; return x.f; }
__device__ __forceinline__ float lo2f(u32 w) { FU x; x.u = w << 16; return x.f; }
__device__ __forceinline__ float hi2f(u32 w) { FU x; x.u = w & 0xffff0000u; return x.f; }
__device__ __forceinline__ u16 f2b(float f) {
  FU x; x.f = f;
  u32 u = x.u;
  u32 r = (u + 0x7FFFu + ((u >> 16) & 1u)) >> 16;
  return (u16)r;
}
__device__ __forceinline__ u32 pk2(float a, float b) {
  __hip_bfloat162 h2 = __float22bfloat162_rn(make_float2(a, b));
  union { __hip_bfloat162 h; u32 u; } c; c.h = h2; return c.u;
}

// ---- fold BN (eval) into A*x+B per layer; layout per layer (320 f32) ----
__global__ void k_bnprep(const float* __restrict__ W, float* __restrict__ bnAB) {
  int idx = blockIdx.x * blockDim.x + threadIdx.x;
  if (idx >= 480) return;
  int i = idx / 160, d0 = idx % 160;
  const float* src; float* dstA; float* dstB; int dim, d;
  if (d0 < 64)       { d = d0;      src = W + 133440 + i * 256; dim = 64; dstA = bnAB + i*320 + 0;   dstB = bnAB + i*320 + 64;  }
  else if (d0 < 80)  { d = d0 - 64; src = W + 134208 + i * 64;  dim = 16; dstA = bnAB + i*320 + 128; dstB = bnAB + i*320 + 144; }
  else if (d0 < 96)  { d = d0 - 80; src = W + 134400 + i * 64;  dim = 16; dstA = bnAB + i*320 + 160; dstB = bnAB + i*320 + 176; }
  else               { d = d0 - 96; src = W + 134592 + i * 256; dim = 64; dstA = bnAB + i*320 + 192; dstB = bnAB + i*320 + 256; }
  float g = src[0*dim+d], b = src[1*dim+d], m = src[2*dim+d], v = src[3*dim+d];
  float A = g * rsqrtf(v + 1e-5f);
  float B = b - m * A;
  dstA[d] = A; dstB[d] = B;
}

// ---- Bsw prep: B-fragment-ordered bf16 Wk2 (for k_msg), K order flat = jp*32+q ----
__global__ void k_prep(const float* __restrict__ W, u16* __restrict__ BswG) {
  int i = blockIdx.x * 256 + threadIdx.x;
  if (i >= 3 * 8704) return;
  int layer = i / 8704, r = i % 8704;
  int jp = r / 512, l2 = r % 512;
  int lane = l2 / 8, j = l2 % 8;
  int q = (lane >> 4) * 8 + j, n = lane & 15;
  const float* Wk2 = W + 103248 + layer * 8704;
  BswG[i] = f2b(Wk2[q * 272 + jp * 16 + n]);
}

// ---- u[i] = normalize(pos[i]-pos[i-1]) ----
__global__ void k_u(const float* __restrict__ posf, float* __restrict__ u) {
  int i = blockIdx.x * blockDim.x + threadIdx.x;
  if (i >= Nn) return;
  float ux, uy, uz;
  if (i == 0) { ux = uy = uz = 0.57735026918962584f; }
  else {
    float vx = posf[i*3+0] - posf[(i-1)*3+0];
    float vy = posf[i*3+1] - posf[(i-1)*3+1];
    float vz = posf[i*3+2] - posf[(i-1)*3+2];
    float nrm = sqrtf(vx*vx + vy*vy + vz*vz);
    float inv = 1.0f / fmaxf(nrm, 1e-12f);
    ux = vx*inv; uy = vy*inv; uz = vz*inv;
  }
  u[i*3+0] = ux; u[i*3+1] = uy; u[i*3+2] = uz;
}

// ---- frame[i] = [b, n, cross(b,n)] stored [j*3+k] ----
__global__ void k_frame(const float* __restrict__ u, float* __restrict__ frame) {
  int i = blockIdx.x * blockDim.x + threadIdx.x;
  if (i >= Nn) return;
  float bx, by, bz, nx, ny, nz;
  if (i < Nn - 1) {
    float ax = u[i*3+0], ay = u[i*3+1], az = u[i*3+2];
    float cx = u[(i+1)*3+0], cy = u[(i+1)*3+1], cz = u[(i+1)*3+2];
    float dx = ax-cx, dy = ay-cy, dz = az-cz;
    float n1 = sqrtf(dx*dx + dy*dy + dz*dz);
    float i1 = 1.0f / fmaxf(n1, 1e-12f);
    bx = dx*i1; by = dy*i1; bz = dz*i1;
    float qx = ay*cz - az*cy, qy = az*cx - ax*cz, qz = ax*cy - ay*cx;
    float n2 = sqrtf(qx*qx + qy*qy + qz*qz);
    float i2 = 1.0f / fmaxf(n2, 1e-12f);
    nx = qx*i2; ny = qy*i2; nz = qz*i2;
  } else {
    bx = by = bz = 0.57735026918962584f;
    nx = ny = nz = 0.57735026918962584f;
  }
  float ex = by*nz - bz*ny, ey = bz*nx - bx*nz, ez = bx*ny - by*nx;
  frame[i*9+0] = bx; frame[i*9+1] = nx; frame[i*9+2] = ex;
  frame[i*9+3] = by; frame[i*9+4] = ny; frame[i*9+5] = ey;
  frame[i*9+6] = bz; frame[i*9+7] = nz; frame[i*9+8] = ez;
}

// ---- per-edge geometry (layer-invariant): t,r -> f32 SoA; + degree count ----
__global__ void k_edge(const int* __restrict__ EI, const float* __restrict__ posf,
                       const float* __restrict__ frame,
                       float* __restrict__ t0, float* __restrict__ t1, float* __restrict__ t2,
                       float* __restrict__ r0, float* __restrict__ r1, float* __restrict__ r2,
                       int* __restrict__ cnt) {
  int e = blockIdx.x * 256 + threadIdx.x;
  int vin = EI[e], vout = EI[Ne + e];
  float fi[9], fo[9];
#pragma unroll
  for (int t = 0; t < 9; t++) fi[t] = frame[(size_t)vin*9 + t];
#pragma unroll
  for (int t = 0; t < 9; t++) fo[t] = frame[(size_t)vout*9 + t];
  float d0 = posf[vout*3+0] - posf[vin*3+0];
  float d1 = posf[vout*3+1] - posf[vin*3+1];
  float d2 = posf[vout*3+2] - posf[vin*3+2];
  float tt[3], rr[3];
#pragma unroll
  for (int k = 0; k < 3; k++) {
    tt[k] = fi[0*3+k]*d0 + fi[1*3+k]*d1 + fi[2*3+k]*d2;
    rr[k] = fi[0*3+k]*fo[0*3+k] + fi[1*3+k]*fo[1*3+k] + fi[2*3+k]*fo[2*3+k];
  }
  t0[e] = tt[0]; t1[e] = tt[1]; t2[e] = tt[2];
  r0[e] = rr[0]; r1[e] = rr[1]; r2[e] = rr[2];
  atomicAdd(&cnt[vout], 1);
}

// ---- multi-block scan ----
__global__ __launch_bounds__(1024) void k_scan1(const int* __restrict__ cnt,
                                                int* __restrict__ locExc,
                                                int* __restrict__ btot) {
  __shared__ int sm[1024];
  int t = threadIdx.x, b = blockIdx.x;
  int i = b * 1024 + t;
  int v = (i < Nn) ? cnt[i] : 0;
  sm[t] = v;
  __syncthreads();
#pragma unroll
  for (int off = 1; off < 1024; off <<= 1) {
    int x = (t >= off) ? sm[t - off] : 0;
    __syncthreads();
    sm[t] += x;
    __syncthreads();
  }
  if (i < Nn) locExc[i] = sm[t] - v;
  if (t == 1023) btot[b] = sm[1023];
}

__global__ void k_scan2(const int* __restrict__ btot, int* __restrict__ boff,
                        int* __restrict__ rowptr) {
  if (threadIdx.x != 0 || blockIdx.x != 0) return;
  int run = 0;
  for (int b = 0; b < SCAN_B; b++) { boff[b] = run; run += btot[b]; }
  rowptr[Nn] = run;
}

__global__ void k_scan3(const int* __restrict__ cnt, const int* __restrict__ locExc,
                        const int* __restrict__ boff, int* __restrict__ rowptr,
                        float* __restrict__ deginv) {
  int i = blockIdx.x * blockDim.x + threadIdx.x;
  if (i >= Nn) return;
  rowptr[i] = locExc[i] + boff[i >> 10];
  int dv = cnt[i] > 1 ? cnt[i] : 1;
  deginv[i] = 1.0f / (float)dv;
}

// ---- place: CSR-ordered Y-offsets + inverse permutation ----
__global__ void k_place(const int* __restrict__ EI, const int* __restrict__ EREL,
                        const int* __restrict__ rowptr,
                        int* __restrict__ fill, int* __restrict__ yidx,
                        int* __restrict__ inv) {
  int e = blockIdx.x * blockDim.x + threadIdx.x;
  if (e >= Ne) return;
  int vout = EI[Ne + e];
  int p = atomicAdd(&fill[vout], 1);
  int slot = rowptr[vout] + p;
  inv[e] = slot;
  yidx[slot] = EI[e] * 448 + EREL[e] * 64;
}

// ---- scalar rel (R8 known-good): Y[n,r,k]; S[n,k] (both bf16) ----
__global__ __launch_bounds__(256) void k_rel(
    const float* __restrict__ h, const float* __restrict__ Wrel,
    const float* __restrict__ Wself, const float* __restrict__ brel,
    const float* __restrict__ bself, u16* __restrict__ Y, u16* __restrict__ S) {
  __shared__ float hs[32][64];
  int tid = threadIdx.x;
  int lane = tid & 63, w = tid >> 6;
  int nb0 = blockIdx.x * 32;
#pragma unroll
  for (int r = 0; r < 8; r++) {
    int idx = r * 256 + tid;
    int row = idx >> 6, col = idx & 63;
    int node = nb0 + row;
    hs[row][col] = (node < Nn) ? h[(size_t)node * 64 + col] : 0.0f;
  }
  __syncthreads();
  int base = w * 8;
  float bias = brel[lane] + bself[lane];
  float acc[8][8];
#pragma unroll
  for (int m = 0; m < 8; m++) {
#pragma unroll
    for (int r = 0; r < 7; r++) acc[m][r] = 0.0f;
    acc[m][7] = bias;
  }
  for (int c = 0; c < 64; c++) {
    float wv[8];
#pragma unroll
    for (int r = 0; r < 7; r++) wv[r] = Wrel[(r*64 + c)*64 + lane];
    wv[7] = Wself[c*64 + lane];
#pragma unroll
    for (int m = 0; m < 8; m++) {
      float hv = hs[base + m][c];
#pragma unroll
      for (int r = 0; r < 8; r++) acc[m][r] += hv * wv[r];
    }
  }
#pragma unroll
  for (int m = 0; m < 8; m++) {
    int node = nb0 + base + m;
    if (node >= Nn) continue;
#pragma unroll
    for (int r = 0; r < 7; r++) Y[(size_t)node*448 + r*64 + lane] = f2b(acc[m][r]);
    S[(size_t)node*64 + lane] = f2b(acc[m][7]);
  }
}

// ---- per-node z + bias precompute ----
__global__ __launch_bounds__(256) void k_z(
    const float* __restrict__ h, const float* __restrict__ Wl1, const float* __restrict__ bl1,
    const float* __restrict__ bk2, const float* __restrict__ bn,
    u16* __restrict__ zt, u16* __restrict__ biast) {
  __shared__ float ls[64][65];
  __shared__ float zz[64][17];
  int tid = threadIdx.x;
  int nb0 = blockIdx.x * 64;
  const float* Ain = bn + 0;
  const float* Bin = bn + 64;
#pragma unroll
  for (int r = 0; r < 16; r++) {
    int idx = r * 256 + tid;
    int row = idx >> 6, col = idx & 63;
    int node = nb0 + row;
    float v = (node < Nn) ? h[(size_t)node * 64 + col] : 0.0f;
    ls[row][col] = fmaxf(v * Ain[col] + Bin[col], 0.0f);
  }
  __syncthreads();
  int row = tid >> 2, jq = (tid & 3) * 4;
  int node = nb0 + row;
  const float* Amsg = bn + 128;
  const float* Bmsg = bn + 144;
  float m1[4];
#pragma unroll
  for (int t = 0; t < 4; t++) m1[t] = bl1[jq + t];
  for (int c = 0; c < 64; c++) {
    float lv = ls[row][c];
#pragma unroll
    for (int t = 0; t < 4; t++) m1[t] += lv * Wl1[c * 16 + jq + t];
  }
  float zv[4];
#pragma unroll
  for (int t = 0; t < 4; t++) {
    zv[t] = fmaxf(m1[t] * Amsg[jq + t] + Bmsg[jq + t], 0.0f);
    zz[row][jq + t] = zv[t];
  }
  if (node < Nn) {
    u32* zg = (u32*)zt + (size_t)node * 8 + (tid & 3) * 2;
    zg[0] = pk2(zv[0], zv[1]);
    zg[1] = pk2(zv[2], zv[3]);
  }
  __syncthreads();
  float bb[4];
#pragma unroll
  for (int t = 0; t < 4; t++) bb[t] = bk2[jq + t];
  for (int j = 0; j < 16; j++) {
    float zj = zz[row][j];
#pragma unroll
    for (int t = 0; t < 4; t++) bb[t] += zj * bk2[(j + 1) * 16 + jq + t];
  }
  if (node < Nn) {
    u32* bg = (u32*)biast + (size_t)node * 8 + (tid & 3) * 2;
    bg[0] = pk2(bb[0], bb[1]);
    bg[1] = pk2(bb[2], bb[3]);
  }
}

// ---- per-edge MFMA kernel (geometry precomputed) ----
__global__ __launch_bounds__(256) void k_msg(
    const float* __restrict__ t0, const float* __restrict__ t1, const float* __restrict__ t2,
    const float* __restrict__ r0, const float* __restrict__ r1, const float* __restrict__ r2,
    const int* __restrict__ EI, const int* __restrict__ inv,
    const u16* __restrict__ zt, const u16* __restrict__ biast,
    const float* __restrict__ Wk1, const float* __restrict__ bk1,
    const u16* __restrict__ BswG, u16* __restrict__ mo) {
  __shared__ u16 abuf[256 * 72];   // a[0:32] | z[32:48] | bias[48:64] | pad -> 36864 B
  __shared__ u32 bsw[4352];        // 17408 B

  int tid = threadIdx.x;
  int e0 = blockIdx.x * 256;
  int e = e0 + tid;

  for (int i = tid; i < 4352; i += 256) bsw[i] = ((const u32*)BswG)[i];

  int vin = EI[e], vout = EI[Ne + e];

  {
    const uint4* zg = (const uint4*)(zt + (size_t)vin * 16);
    uint4* zr = (uint4*)(abuf + (size_t)tid * 72 + 32);
    zr[0] = zg[0]; zr[1] = zg[1];
    const uint4* bg = (const uint4*)(biast + (size_t)vin * 16);
    uint4* br = (uint4*)(abuf + (size_t)tid * 72 + 48);
    br[0] = bg[0]; br[1] = bg[1];
  }

  float ef[14];
  ef[0] = t0[e]; ef[1] = t1[e]; ef[2] = t2[e];
  ef[3] = r0[e]; ef[4] = r1[e]; ef[5] = r2[e];
  int ad = vin - vout; if (ad < 0) ad = -ad;
  ef[6] = ((float)ad) / 6.0f;
#pragma unroll
  for (int k = 0; k < 7; k++) ef[7+k] = 1.0f - 2.0f*fabsf(ef[k]);

  float a[32];
#pragma unroll
  for (int q = 0; q < 32; q++) a[q] = bk1[q];
#pragma unroll
  for (int d = 0; d < 14; d++) {
    float fv = ef[d];
#pragma unroll
    for (int q = 0; q < 32; q++) a[q] += fv * Wk1[d*32 + q];
  }
  u32* ar = (u32*)(abuf + (size_t)tid * 72);
#pragma unroll
  for (int q = 0; q < 16; q++)
    ar[q] = pk2(fmaxf(a[2*q], 0.0f), fmaxf(a[2*q+1], 0.0f));
  __syncthreads();

  int lane = tid & 63, w4 = (tid >> 6) * 4;
  int m = lane & 15, quad = lane >> 4;
  union U { uint4 u; short8 v; };
#pragma unroll
  for (int t = 0; t < 4; t++) {
    int s0 = (w4 + t) * 16;
    int s = s0 + m;
    const u16* rs = abuf + (size_t)s * 72;
    U afr;
    afr.u = *(const uint4*)(rs + quad * 8);
    const u32* aw = (const u32*)&afr.u;
    float av[8];
#pragma unroll
    for (int j = 0; j < 4; j++) { av[2*j] = lo2f(aw[j]); av[2*j+1] = hi2f(aw[j]); }

    uint4 zu0 = *(const uint4*)(rs + 32);
    uint4 zu1 = *(const uint4*)(rs + 40);
    const u32* zw0 = (const u32*)&zu0;
    const u32* zw1 = (const u32*)&zu1;
    float zf[16];
#pragma unroll
    for (int j = 0; j < 4; j++) {
      zf[2*j]   = lo2f(zw0[j]); zf[2*j+1]   = hi2f(zw0[j]);
      zf[8+2*j] = lo2f(zw1[j]); zf[8+2*j+1] = hi2f(zw1[j]);
    }

    floatx4 acc = {0.0f, 0.0f, 0.0f, 0.0f};
    U bfr;
    bfr.u = *(const uint4*)(bsw + (size_t)(0 * 64 + lane) * 4);
    acc = __builtin_amdgcn_mfma_f32_16x16x32_bf16(afr.v, bfr.v, acc, 0, 0, 0);

#pragma unroll
    for (int jp = 1; jp < 17; jp++) {
      float zv = zf[jp - 1];
      U pf;
      u32* pw = (u32*)&pf.u;
#pragma unroll
      for (int j = 0; j < 4; j++)
        pw[j] = pk2(av[2*j] * zv, av[2*j+1] * zv);
      bfr.u = *(const uint4*)(bsw + (size_t)(jp * 64 + lane) * 4);
      acc = __builtin_amdgcn_mfma_f32_16x16x32_bf16(pf.v, bfr.v, acc, 0, 0, 0);
    }

    int k = m;
#pragma unroll
    for (int reg = 0; reg < 4; reg++) {
      int se = s0 + quad * 4 + reg;
      float bias = b2f(abuf[(size_t)se * 72 + 48 + k]);
      int slot = inv[e0 + se];
      mo[(size_t)slot * 16 + k] = f2b(acc[reg] + bias);
    }
  }
}

// ---- per-node: prefetched Y gather + sequential mo, residual, LN ----
__global__ __launch_bounds__(256) void k_node(
    const float* __restrict__ h, const u16* __restrict__ S, const u16* __restrict__ Y,
    const int* __restrict__ rowptr, const int* __restrict__ yidx,
    const u16* __restrict__ mo, const float* __restrict__ deginv,
    const float* __restrict__ Wl2, const float* __restrict__ bl2,
    const float* __restrict__ bn, const float* __restrict__ lng, const float* __restrict__ lnb,
    float* __restrict__ hout) {
  __shared__ float u2s[4][16];
  int tid = threadIdx.x;
  int lane = tid & 63, w = tid >> 6;
  int n = blockIdx.x * 4 + w;
  bool act = (n < Nn);

  float acc = 0.0f;
  float partial = 0.0f;
  if (act) {
    int beg = rowptr[n], end = rowptr[n+1];
    acc = b2f(S[(size_t)n*64 + lane]);
    for (int c0 = beg; c0 < end; c0 += 64) {
      int l = c0 + lane;
      int yo = (l < end) ? yidx[l] : 0;
      int cnt = end - c0; if (cnt > 64) cnt = 64;
      for (int j = 0; j < cnt; j++) {
        int yoj = __shfl(yo, j, 64);
        acc += b2f(Y[(size_t)yoj + lane]);
      }
    }
    int g = lane >> 4, k = lane & 15;
    for (int p = beg + g; p < end; p += 4)
      partial += b2f(mo[(size_t)p*16 + k]);
  }
  partial += __shfl_xor(partial, 16, 64);
  partial += __shfl_xor(partial, 32, 64);
  const float* Aupd = bn + 160;
  const float* Bupd = bn + 176;
  if (act && lane < 16) {
    float v = partial * deginv[n];
    u2s[w][lane] = fmaxf(v * Aupd[lane] + Bupd[lane], 0.0f);
  }
  __syncthreads();
  if (act) {
    float rel_out = fmaxf(acc, 0.0f);
    float ie = bl2[lane];
#pragma unroll
    for (int j = 0; j < 16; j++) ie += u2s[w][j] * Wl2[j*64 + lane];
    const float* Aout = bn + 192;
    const float* Bout = bn + 256;
    ie = ie * Aout[lane] + Bout[lane];
    float hidden = rel_out + ie + h[(size_t)n*64 + lane];
    float s = hidden;
#pragma unroll
    for (int off = 32; off > 0; off >>= 1) s += __shfl_xor(s, off, 64);
    float mu = s * (1.0f/64.0f);
    float d = hidden - mu;
    float s2 = d * d;
#pragma unroll
    for (int off = 32; off > 0; off >>= 1) s2 += __shfl_xor(s2, off, 64);
    float var = s2 * (1.0f/64.0f);
    float o = d * rsqrtf(var + 1e-5f) * lng[lane] + lnb[lane];
    hout[(size_t)n*64 + lane] = o;
  }
}

extern "C" void kernel_launch(void* const* d_in, const int* in_sizes, int n_in,
                              void* d_out, int out_size, void* d_ws, size_t ws_size,
                              hipStream_t stream) {
  const float* x    = (const float*)d_in[0];
  const float* posf = (const float*)d_in[1];
  const int* EI     = (const int*)d_in[2];
  const int* EREL   = (const int*)d_in[3];
  float* outf       = (float*)d_out;

  char* p = (char*)d_ws;
  auto alloc = [&](size_t bytes) -> char* {
    char* r = p;
    p += (bytes + 255) & ~((size_t)255);
    return r;
  };
  float* W      = (float*)alloc((size_t)135744 * 4);
  float* bnAB   = (float*)alloc((size_t)960 * 4);
  u16*   BswG   = (u16*)  alloc((size_t)3 * 8704 * 2);
  float* u      = (float*)alloc((size_t)Nn * 3 * 4);
  float* frame  = (float*)alloc((size_t)Nn * 9 * 4);
  int*   cnt    = (int*)  alloc((size_t)Nn * 4);
  int*   fill   = (int*)  alloc((size_t)Nn * 4);
  int*   rowptr = (int*)  alloc((size_t)(Nn + 1) * 4);
  int*   locExc = (int*)  alloc((size_t)Nn * 4);
  int*   btot   = (int*)  alloc((size_t)SCAN_B * 4);
  int*   boff   = (int*)  alloc((size_t)SCAN_B * 4);
  int*   yidx   = (int*)  alloc((size_t)Ne * 4);
  int*   inv    = (int*)  alloc((size_t)Ne * 4);
  float* deginv = (float*)alloc((size_t)Nn * 4);
  float* h      = (float*)alloc((size_t)Nn * 64 * 4);
  u16*   S      = (u16*)  alloc((size_t)Nn * 64 * 2);
  u16*   Y      = (u16*)  alloc((size_t)Nn * 448 * 2);
  u16*   mo     = (u16*)  alloc((size_t)Ne * 16 * 2);
  u16*   zt     = (u16*)  alloc((size_t)Nn * 16 * 2);
  u16*   biast  = (u16*)  alloc((size_t)Nn * 16 * 2);
  float* et0    = (float*)alloc((size_t)Ne * 4);
  float* et1    = (float*)alloc((size_t)Ne * 4);
  float* et2    = (float*)alloc((size_t)Ne * 4);
  float* er0    = (float*)alloc((size_t)Ne * 4);
  float* er1    = (float*)alloc((size_t)Ne * 4);
  float* er2    = (float*)alloc((size_t)Ne * 4);
  (void)n_in; (void)in_sizes; (void)out_size;

  size_t needed = (size_t)(p - (char*)d_ws);
  if (needed > ws_size) return;  // diagnostic: zero output => absmax == max|ref| (~4.75)

  hipMemsetAsync(cnt,  0, (size_t)Nn * 4, stream);
  hipMemsetAsync(fill, 0, (size_t)Nn * 4, stream);

  for (int k = 0; k < 18; k++)
    hipMemcpyAsync(W + H_CUM[k], d_in[4 + k], (size_t)H_SZ[k] * 4,
                   hipMemcpyDeviceToDevice, stream);
  hipMemcpyAsync(h, x, (size_t)Nn * 64 * 4, hipMemcpyDeviceToDevice, stream);

  k_bnprep<<<2, 256, 0, stream>>>(W, bnAB);
  k_prep<<<(3*8704 + 255)/256, 256, 0, stream>>>(W, BswG);
  k_u<<<(Nn + 255)/256, 256, 0, stream>>>(posf, u);
  k_frame<<<(Nn + 255)/256, 256, 0, stream>>>(u, frame);
  k_edge<<<Ne/256, 256, 0, stream>>>(EI, posf, frame, et0, et1, et2, er0, er1, er2, cnt);
  k_scan1<<<SCAN_B, 1024, 0, stream>>>(cnt, locExc, btot);
  k_scan2<<<1, 64, 0, stream>>>(btot, boff, rowptr);
  k_scan3<<<(Nn + 255)/256, 256, 0, stream>>>(cnt, locExc, boff, rowptr, deginv);
  k_place<<<Ne/256, 256, 0, stream>>>(EI, EREL, rowptr, fill, yidx, inv);

  for (int i = 0; i < Ll; i++) {
    const float* Wrel  = W + H_CUM[0]  + i * 28672;
    const float* brel  = W + H_CUM[1]  + i * 64;
    const float* Wself = W + H_CUM[2]  + i * 4096;
    const float* bself = W + H_CUM[3]  + i * 64;
    const float* Wl1   = W + H_CUM[4]  + i * 1024;
    const float* bl1   = W + H_CUM[5]  + i * 16;
    const float* Wk1   = W + H_CUM[6]  + i * 448;
    const float* bk1   = W + H_CUM[7]  + i * 32;
    const float* bk2   = W + H_CUM[9]  + i * 272;
    const float* Wl2   = W + H_CUM[10] + i * 1024;
    const float* bl2   = W + H_CUM[11] + i * 64;
    const float* lng   = W + H_CUM[16] + i * 64;
    const float* lnb   = W + H_CUM[17] + i * 64;
    const float* bnL   = bnAB + i * 320;
    const u16*   BswL  = BswG + i * 8704;

    k_rel<<<Nn/32, 256, 0, stream>>>(h, Wrel, Wself, brel, bself, Y, S);
    k_z<<<(Nn + 63)/64, 256, 0, stream>>>(h, Wl1, bl1, bk2, bnL, zt, biast);
    k_msg<<<Ne/256, 256, 0, stream>>>(et0, et1, et2, er0, er1, er2, EI, inv,
                                      zt, biast, Wk1, bk1, BswL, mo);
    k_node<<<(Nn + 3)/4, 256, 0, stream>>>(h, S, Y, rowptr, yidx, mo, deginv,
                                           Wl2, bl2, bnL, lng, lnb,
                                           (i == Ll - 1) ? outf : h);
  }
}